// Round 12
// baseline (242.625 us; speedup 1.0000x reference)
//
#include <hip/hip_runtime.h>
#include <hip/hip_bf16.h>

// Problem constants
#define B_    2
#define QN    100
#define NP    6
#define WS2   49
#define CC    256
#define NHH   8
#define HDD   32
#define NWIN  600            // Q*Np windows per batch
#define O_PER_B 7526400      // NH*WS2*NWIN*HD

// ws layout (bytes): xT fp32 | wbp bf16 frag-packed [48][8][64][8] | qkv bf16 [1200][49][768] | O fp32
#define XT_BYTES   8388608
#define WB_BYTES   393216
#define QKV_SHORTS_PER_WIN (WS2 * 768)      // 37632 shorts
#define QKV_BYTES  (1200 * WS2 * 768 * 2)   // 90316800

#define SPB_LD 264   // bf16 sp row stride (shorts)
#define CW_LD  72    // per-wave C line-assembly row stride (144B rows, 16B-aligned)

typedef __attribute__((ext_vector_type(8))) short bf16x8;
typedef __attribute__((ext_vector_type(4))) float f32x4;

__device__ __forceinline__ unsigned short f2bf(float f) {
  union { float f; unsigned int i; } v; v.f = f;
  unsigned int x = v.i;
  x += 0x7fffu + ((x >> 16) & 1u);   // round-to-nearest-even
  return (unsigned short)(x >> 16);
}

// ---------- K0: fused x-transpose (blocks 0..2047) + w_qkv pack (blocks 2048..2143) ----------
__global__ void k0_prep(const float* __restrict__ x, float* __restrict__ xT,
                        const float* __restrict__ w_qkv, unsigned short* __restrict__ wbp) {
  __shared__ float tile[32][33];
  const int gb = blockIdx.x;
  if (gb < 2048) {
    int b   = gb >> 10;
    int rem = gb & 1023;
    int hw0 = (rem & 127) * 32;
    int c0  = (rem >> 7) * 32;
    int tx = threadIdx.x & 31, ty = threadIdx.x >> 5;   // 32x8
    const float* src = x + (size_t)b * CC * 4096;
    float* dst = xT + (size_t)b * 4096 * CC;
    #pragma unroll
    for (int i = ty; i < 32; i += 8)
      tile[i][tx] = src[(size_t)(c0 + i) * 4096 + hw0 + tx];
    __syncthreads();
    #pragma unroll
    for (int i = ty; i < 32; i += 8)
      dst[(size_t)(hw0 + i) * CC + c0 + tx] = tile[tx][i];
  } else {
    // wbp[((nt*8+ks)*64+lane)*8+i] = bf16(w_qkv[nt*16+(lane&15)][ks*32+(lane>>4)*8+i])
    int g = (gb - 2048) * 256 + threadIdx.x;      // 0..24575
    int lane = g & 63;
    int ks = (g >> 6) & 7;
    int nt = g >> 9;
    int n  = nt * 16 + (lane & 15);
    int k0 = ks * 32 + (lane >> 4) * 8;
    const float* src = w_qkv + (size_t)n * CC + k0;
    float4 lo = *(const float4*)(src);
    float4 hi = *(const float4*)(src + 4);
    unsigned short o[8] = { f2bf(lo.x), f2bf(lo.y), f2bf(lo.z), f2bf(lo.w),
                            f2bf(hi.x), f2bf(hi.y), f2bf(hi.z), f2bf(hi.w) };
    *(uint4*)(wbp + (size_t)g * 8) = *(uint4*)o;
  }
}

// ---------- K1: per-window sample + MFMA QKV GEMM -> qkv_ws (bf16, [win][r][j]) ----------
// Round-12: 4 blocks/CU push. spb pad rows deleted (af row-clamp to 48 is safe:
// garbage A-rows only feed C-rows>=49, discarded by store guards) -> LDS 35.9KB;
// bfrag double-buffer deleted (-16 regs; 16 waves/CU + compiler vmcnt hoisting
// replace it) -> target <=128 unified regs at launch_bounds(256,4).
__launch_bounds__(256, 4)
__global__ void k1_sample_qkv(const float* __restrict__ xT,
                              const float* __restrict__ polys,
                              const unsigned short* __restrict__ wbp,
                              const float* __restrict__ b_qkv,
                              unsigned short* __restrict__ qkv_ws) {
  __shared__ __align__(16) unsigned short spb[WS2 * SPB_LD];
  __shared__ __align__(16) unsigned short Cwbuf[4][16 * CW_LD];
  __shared__ float co_x0[WS2], co_y0[WS2], co_wx[WS2], co_wy[WS2];
  const int tid = threadIdx.x;
  const int m = blockIdx.x;
  const int b = blockIdx.y;

  // Phase A: coords for the 49 rows of this window (grid scramble: n = m*49+r)
  if (tid < WS2) {
    int n = m * WS2 + tid;
    int q = n / (WS2 * NP);
    int p = (n / NP) % WS2;
    int a = n % NP;
    const float* pc = polys + (size_t)(b * QN + q) * 12;
    float al = (float)a * 0.2f;
    float py = pc[0];
    float px = pc[6];
    #pragma unroll
    for (int i = 1; i < 6; i++) { py = py * al + pc[i]; px = px * al + pc[6 + i]; }
    py = 2.0f * py - 1.0f;
    px = 2.0f * px - 1.0f;
    float gy = py + (2.0f * (-4.0f + (float)(p / 7) * (7.0f / 6.0f))) * (1.0f / 64.0f);
    float gx = px + (2.0f * (-4.0f + (float)(p % 7) * (7.0f / 6.0f))) * (1.0f / 64.0f);
    // NOTE the reference swap: fx from grid_y, fy from grid_x
    float fx = (gy + 1.0f) * 0.5f * 63.0f;
    float fy = (gx + 1.0f) * 0.5f * 63.0f;
    float x0 = floorf(fx), y0 = floorf(fy);
    co_x0[tid] = x0; co_y0[tid] = y0;
    co_wx[tid] = fx - x0; co_wy[tid] = fy - y0;
  }
  __syncthreads();

  // Phase B: bilinear sampling, thread = channel, depth-1 software pipeline
  const float* xb = xT + (size_t)b * (4096 * CC);
  float n00, n01, n10, n11, wxn, wyn;
  {
    float x0 = co_x0[0], y0 = co_y0[0];
    wxn = co_wx[0]; wyn = co_wy[0];
    float x1 = x0 + 1.0f, y1 = y0 + 1.0f;
    int xi0 = (int)fminf(fmaxf(x0, 0.0f), 63.0f);
    int yi0 = (int)fminf(fmaxf(y0, 0.0f), 63.0f);
    int xi1 = (int)fminf(fmaxf(x1, 0.0f), 63.0f);
    int yi1 = (int)fminf(fmaxf(y1, 0.0f), 63.0f);
    bool vx0 = (x0 >= 0.0f) && (x0 <= 63.0f);
    bool vx1 = (x1 >= 0.0f) && (x1 <= 63.0f);
    bool vy0 = (y0 >= 0.0f) && (y0 <= 63.0f);
    bool vy1 = (y1 >= 0.0f) && (y1 <= 63.0f);
    n00 = (vx0 && vy0) ? xb[(yi0 * 64 + xi0) * CC + tid] : 0.0f;
    n01 = (vx1 && vy0) ? xb[(yi0 * 64 + xi1) * CC + tid] : 0.0f;
    n10 = (vx0 && vy1) ? xb[(yi1 * 64 + xi0) * CC + tid] : 0.0f;
    n11 = (vx1 && vy1) ? xb[(yi1 * 64 + xi1) * CC + tid] : 0.0f;
  }
  for (int r = 0; r < WS2; r++) {
    float c00 = n00, c01 = n01, c10 = n10, c11 = n11;
    float wx = wxn, wy = wyn;
    if (r + 1 < WS2) {
      int rn = r + 1;
      float x0 = co_x0[rn], y0 = co_y0[rn];
      wxn = co_wx[rn]; wyn = co_wy[rn];
      float x1 = x0 + 1.0f, y1 = y0 + 1.0f;
      int xi0 = (int)fminf(fmaxf(x0, 0.0f), 63.0f);
      int yi0 = (int)fminf(fmaxf(y0, 0.0f), 63.0f);
      int xi1 = (int)fminf(fmaxf(x1, 0.0f), 63.0f);
      int yi1 = (int)fminf(fmaxf(y1, 0.0f), 63.0f);
      bool vx0 = (x0 >= 0.0f) && (x0 <= 63.0f);
      bool vx1 = (x1 >= 0.0f) && (x1 <= 63.0f);
      bool vy0 = (y0 >= 0.0f) && (y0 <= 63.0f);
      bool vy1 = (y1 >= 0.0f) && (y1 <= 63.0f);
      n00 = (vx0 && vy0) ? xb[(yi0 * 64 + xi0) * CC + tid] : 0.0f;
      n01 = (vx1 && vy0) ? xb[(yi0 * 64 + xi1) * CC + tid] : 0.0f;
      n10 = (vx0 && vy1) ? xb[(yi1 * 64 + xi0) * CC + tid] : 0.0f;
      n11 = (vx1 && vy1) ? xb[(yi1 * 64 + xi1) * CC + tid] : 0.0f;
    }
    float s = c00 * (1.0f - wy) * (1.0f - wx) + c01 * (1.0f - wy) * wx
            + c10 * wy * (1.0f - wx) + c11 * wy * wx;
    spb[r * SPB_LD + tid] = f2bf(s);
  }
  __syncthreads();

  // Phase C: MFMA GEMM. Wave wv owns N-tiles [wv*12,+12) in 3 chunks of 4.
  const int lane = tid & 63;
  const int wv = tid >> 6;
  const int lm = lane & 15;
  const int lg = lane >> 4;
  unsigned short* qd = qkv_ws + (size_t)(b * NWIN + m) * QKV_SHORTS_PER_WIN;
  unsigned short* Cw = &Cwbuf[wv][0];
  // af row clamp: rows >= 49 read row 48 (garbage feeds only discarded C rows)
  int arow[4];
  #pragma unroll
  for (int mt = 0; mt < 4; mt++) {
    int r = mt * 16 + lm;
    arow[mt] = (r > 48) ? 48 : r;
  }

  for (int jc = 0; jc < 3; jc++) {
    const int nt0 = wv * 12 + jc * 4;
    const int ncol0 = nt0 * 16 + lm;
    f32x4 acc[4][4];
    #pragma unroll
    for (int j4 = 0; j4 < 4; j4++) {
      float bias = b_qkv[ncol0 + j4 * 16];
      #pragma unroll
      for (int mt = 0; mt < 4; mt++) acc[mt][j4] = (f32x4){bias, bias, bias, bias};
    }
    #pragma unroll
    for (int ks = 0; ks < 8; ks++) {
      bf16x8 af[4];
      #pragma unroll
      for (int mt = 0; mt < 4; mt++)
        af[mt] = *(const bf16x8*)(spb + arow[mt] * SPB_LD + ks * 32 + lg * 8);
      #pragma unroll
      for (int j4 = 0; j4 < 4; j4++) {
        bf16x8 bfrag = *(const bf16x8*)(wbp + (size_t)(((nt0 + j4) * 8 + ks) * 64 + lane) * 8);
        #pragma unroll
        for (int mt = 0; mt < 4; mt++)
          acc[mt][j4] = __builtin_amdgcn_mfma_f32_16x16x32_bf16(af[mt], bfrag, acc[mt][j4], 0, 0, 0);
      }
    }
    // per-mt 16-row assembly + full-line stores (8 lines per uint4 instr)
    const int cbase = nt0 * 16;
    #pragma unroll
    for (int mt = 0; mt < 4; mt++) {
      #pragma unroll
      for (int reg = 0; reg < 4; reg++) {
        int rr = lg * 4 + reg;   // row within tile
        #pragma unroll
        for (int j4 = 0; j4 < 4; j4++)
          Cw[rr * CW_LD + j4 * 16 + lm] = f2bf(acc[mt][j4][reg]);
      }
      int r0 = mt * 16;
      #pragma unroll
      for (int half = 0; half < 2; half++) {
        int idx = half * 64 + lane;
        int r16 = idx >> 3;       // 0..15
        int seg = idx & 7;
        int r = r0 + r16;
        if (r < WS2)
          *(uint4*)(qd + (size_t)r * 768 + cbase + seg * 8) =
              *(const uint4*)(Cw + r16 * CW_LD + seg * 8);
      }
    }
  }
}

// ---------- K2: MFMA windowed attention, wave-per-head (2 heads/wave) ----------
// r11 full-line O stores kept; round-12: V staging vectorized (uint2, 4x fewer
// global load instrs) with one-time Vt zeroing.
#define P_LD 72    // P row stride in shorts
#define V_LD 72    // Vt row stride in shorts
#define OW_LD 36   // O assembly row stride in floats
#define P_WAVE (WS2 * P_LD)          // 3528 shorts per wave
#define V_OFF  (4 * P_WAVE)          // 14112 shorts
#define V_WAVE (32 * V_LD)           // 2304 shorts per wave
__launch_bounds__(256, 3)
__global__ void k2_attn(const unsigned short* __restrict__ qkv_ws,
                        float* __restrict__ o_ws) {
  __shared__ __align__(16) unsigned short lds[V_OFF + 4 * V_WAVE];  // 46656 B
  const int tid = threadIdx.x;
  const int lane = tid & 63;
  const int wv = tid >> 6;
  const int lm = lane & 15;
  const int lg = lane >> 4;
  const int m = blockIdx.x;
  const int b = blockIdx.y;
  const unsigned short* wsrc = qkv_ws + (size_t)(b * NWIN + m) * QKV_SHORTS_PER_WIN;
  const float scale = 0.17677669529663687f;  // 1/sqrt(32)
  unsigned short* P  = lds + wv * P_WAVE;
  unsigned short* Vt = lds + V_OFF + wv * V_WAVE;
  float* Ow = (float*)P;   // O assembly reuses P region after PV (same-wave ds order)

  // zero Vt once (rows r>=49 must be 0; bf16-NaN garbage x P=0 would make NaN)
  {
    unsigned int* vz = (unsigned int*)Vt;
    #pragma unroll
    for (int i = 0; i < 18; i++) vz[i * 64 + lane] = 0u;
  }

  for (int hh = 0; hh < 2; hh++) {
    const int h = wv * 2 + hh;

    // Stage V^T: Vt[d][r] from wsrc[r*768+512+h*32+d], uint2 (4 shorts) per lane
    for (int i = 0; i < 7; i++) {
      int idx = i * 64 + lane;          // (r, dgroup): idx = r*8 + dg
      if (idx < WS2 * 8) {
        int r = idx >> 3;
        int d0 = (idx & 7) * 4;
        const unsigned short* pp = wsrc + (size_t)r * 768 + 512 + h * HDD + d0;
        uint2 u = *(const uint2*)pp;
        Vt[(d0 + 0) * V_LD + r] = (unsigned short)(u.x & 0xffffu);
        Vt[(d0 + 1) * V_LD + r] = (unsigned short)(u.x >> 16);
        Vt[(d0 + 2) * V_LD + r] = (unsigned short)(u.y & 0xffffu);
        Vt[(d0 + 3) * V_LD + r] = (unsigned short)(u.y >> 16);
      }
    }

    // Q/K fragments straight from global [r][j], row-clamped
    bf16x8 qf[4], kf[4];
    #pragma unroll
    for (int t = 0; t < 4; t++) {
      int r = t * 16 + lm; if (r > 48) r = 48;
      qf[t] = *(const bf16x8*)(wsrc + (size_t)r * 768 + h * HDD + lg * 8);
      kf[t] = *(const bf16x8*)(wsrc + (size_t)r * 768 + 256 + h * HDD + lg * 8);
    }

    // S = Q K^T
    f32x4 s[4][4];
    #pragma unroll
    for (int mt = 0; mt < 4; mt++)
      #pragma unroll
      for (int nt = 0; nt < 4; nt++) {
        s[mt][nt] = (f32x4){0.f, 0.f, 0.f, 0.f};
        s[mt][nt] = __builtin_amdgcn_mfma_f32_16x16x32_bf16(qf[mt], kf[nt], s[mt][nt], 0, 0, 0);
      }

    #pragma unroll
    for (int mt = 0; mt < 4; mt++)
      #pragma unroll
      for (int nt = 0; nt < 4; nt++) {
        bool badcol = (nt == 3) && (lm > 0);
        #pragma unroll
        for (int reg = 0; reg < 4; reg++)
          s[mt][nt][reg] = badcol ? -1e30f : s[mt][nt][reg] * scale;
      }

    // softmax over keys (pos_bias is per-row constant: cancels exactly)
    #pragma unroll
    for (int mt = 0; mt < 4; mt++) {
      #pragma unroll
      for (int reg = 0; reg < 4; reg++) {
        float mx = fmaxf(fmaxf(s[mt][0][reg], s[mt][1][reg]),
                         fmaxf(s[mt][2][reg], s[mt][3][reg]));
        #pragma unroll
        for (int off = 1; off < 16; off <<= 1) mx = fmaxf(mx, __shfl_xor(mx, off));
        float sum = 0.0f;
        #pragma unroll
        for (int nt = 0; nt < 4; nt++) {
          float e = __expf(s[mt][nt][reg] - mx);
          s[mt][nt][reg] = e;
          sum += e;
        }
        #pragma unroll
        for (int off = 1; off < 16; off <<= 1) sum += __shfl_xor(sum, off);
        float inv = 1.0f / sum;
        #pragma unroll
        for (int nt = 0; nt < 4; nt++) s[mt][nt][reg] *= inv;
      }
    }

    // P (bf16) -> LDS row-major [p][r2]; cols 49..63 are exact zeros
    #pragma unroll
    for (int mt = 0; mt < 4; mt++)
      #pragma unroll
      for (int nt = 0; nt < 4; nt++)
        #pragma unroll
        for (int reg = 0; reg < 4; reg++) {
          int p = mt * 16 + lg * 4 + reg;
          if (p < WS2) P[p * P_LD + nt * 16 + lm] = f2bf(s[mt][nt][reg]);
        }

    // O = P V
    f32x4 o[4][2];
    #pragma unroll
    for (int mt = 0; mt < 4; mt++)
      #pragma unroll
      for (int nt2 = 0; nt2 < 2; nt2++) o[mt][nt2] = (f32x4){0.f, 0.f, 0.f, 0.f};
    #pragma unroll
    for (int ks = 0; ks < 2; ks++) {
      bf16x8 vf[2];
      #pragma unroll
      for (int nt2 = 0; nt2 < 2; nt2++)
        vf[nt2] = *(const bf16x8*)(Vt + (nt2 * 16 + lm) * V_LD + ks * 32 + lg * 8);
      #pragma unroll
      for (int mt = 0; mt < 4; mt++) {
        bf16x8 af = *(const bf16x8*)(P + (mt * 16 + lm) * P_LD + ks * 32 + lg * 8);
        #pragma unroll
        for (int nt2 = 0; nt2 < 2; nt2++)
          o[mt][nt2] = __builtin_amdgcn_mfma_f32_16x16x32_bf16(af, vf[nt2], o[mt][nt2], 0, 0, 0);
      }
    }

    // O -> LDS assembly (P region dead after PV; same-wave ds program order)
    #pragma unroll
    for (int mt = 0; mt < 4; mt++)
      #pragma unroll
      for (int reg = 0; reg < 4; reg++) {
        int p = mt * 16 + lg * 4 + reg;
        if (p < WS2) {
          #pragma unroll
          for (int nt2 = 0; nt2 < 2; nt2++)
            Ow[p * OW_LD + nt2 * 16 + lm] = o[mt][nt2][reg];
        }
      }
    // full-line stores: 8 lanes x uint4 = one complete 128B line per row
    float* ob = o_ws + (size_t)b * O_PER_B + ((size_t)h * WS2 * NWIN + m) * HDD;
    for (int idx = lane; idx < WS2 * 8; idx += 64) {
      int p = idx >> 3, seg = idx & 7;
      *(uint4*)(ob + (size_t)p * (NWIN * HDD) + seg * 4) =
          *(const uint4*)(Ow + p * OW_LD + seg * 4);
    }
  }
}

// ---------- K3: conv (49-tap over p') + projection ----------
__global__ void k3_conv_proj(const float* __restrict__ o_ws,
                             const float* __restrict__ conv_w,
                             const float* __restrict__ conv_b,
                             const float* __restrict__ w_proj,
                             const float* __restrict__ b_proj,
                             float* __restrict__ out) {
  __shared__ float yv[CC];
  __shared__ float cw[WS2];
  const int tid = threadIdx.x;
  const int np = blockIdx.x;
  const int b = blockIdx.y;
  if (tid < WS2) cw[tid] = conv_w[tid];
  __syncthreads();
  const float* base = o_ws + (size_t)b * O_PER_B + (size_t)np * (WS2 * CC);
  float acc = conv_b[0];
  for (int p = 0; p < WS2; p++)
    acc += cw[p] * base[p * CC + tid];
  yv[tid] = acc;
  __syncthreads();
  const float4* y4 = (const float4*)yv;
  const float4* w4 = (const float4*)(w_proj + (size_t)tid * CC);
  float s = b_proj[tid];
  float s2 = 0.0f;
  #pragma unroll 8
  for (int c4 = 0; c4 < 64; c4++) {
    float4 a = y4[c4], wv2 = w4[c4];
    s2 += a.x * wv2.x + a.y * wv2.y + a.z * wv2.z + a.w * wv2.w;
  }
  out[((size_t)(b * NWIN + np)) * CC + tid] = s + s2;
}

extern "C" void kernel_launch(void* const* d_in, const int* in_sizes, int n_in,
                              void* d_out, int out_size, void* d_ws, size_t ws_size,
                              hipStream_t stream) {
  const float* x        = (const float*)d_in[0];
  const float* polys    = (const float*)d_in[1];
  const float* w_qkv    = (const float*)d_in[2];
  const float* b_qkv    = (const float*)d_in[3];
  const float* w_proj   = (const float*)d_in[4];
  const float* b_proj   = (const float*)d_in[5];
  const float* conv_w   = (const float*)d_in[6];
  const float* conv_b   = (const float*)d_in[7];
  float* out = (float*)d_out;

  char* ws = (char*)d_ws;
  float* xT = (float*)ws;
  unsigned short* wbp = (unsigned short*)(ws + XT_BYTES);
  unsigned short* qkv_ws = (unsigned short*)(ws + XT_BYTES + WB_BYTES);
  float* o_ws = (float*)(ws + XT_BYTES + WB_BYTES + QKV_BYTES);

  hipLaunchKernelGGL(k0_prep, dim3(2144), dim3(256), 0, stream, x, xT, w_qkv, wbp);
  hipLaunchKernelGGL(k1_sample_qkv, dim3(NWIN, B_), dim3(256), 0, stream,
                     xT, polys, wbp, b_qkv, qkv_ws);
  hipLaunchKernelGGL(k2_attn, dim3(NWIN, B_), dim3(256), 0, stream,
                     qkv_ws, o_ws);
  hipLaunchKernelGGL(k3_conv_proj, dim3(NWIN, B_), dim3(256), 0, stream,
                     o_ws, conv_w, conv_b, w_proj, b_proj, out);
}

// Round 13
// 213.641 us; speedup vs baseline: 1.1357x; 1.1357x over previous
//
#include <hip/hip_runtime.h>
#include <hip/hip_bf16.h>

// Problem constants
#define B_    2
#define QN    100
#define NP    6
#define WS2   49
#define CC    256
#define NHH   8
#define HDD   32
#define NWIN  600            // Q*Np windows per batch
#define O_PER_B 7526400      // NH*WS2*NWIN*HD

// ws layout (bytes): xT fp32 | wbp bf16 frag-packed [48][8][64][8] | qkv bf16 [1200][49][768] | O fp32
#define XT_BYTES   8388608
#define WB_BYTES   393216
#define QKV_SHORTS_PER_WIN (WS2 * 768)      // 37632 shorts
#define QKV_BYTES  (1200 * WS2 * 768 * 2)   // 90316800

#define SPB_LD 264   // bf16 sp row stride (shorts)
#define CW_LD  72    // per-wave C line-assembly row stride (144B rows, 16B-aligned)

typedef __attribute__((ext_vector_type(8))) short bf16x8;
typedef __attribute__((ext_vector_type(4))) float f32x4;

__device__ __forceinline__ unsigned short f2bf(float f) {
  union { float f; unsigned int i; } v; v.f = f;
  unsigned int x = v.i;
  x += 0x7fffu + ((x >> 16) & 1u);   // round-to-nearest-even
  return (unsigned short)(x >> 16);
}

// ---------- K0: fused x-transpose (blocks 0..2047) + w_qkv pack (blocks 2048..2143) ----------
__global__ void k0_prep(const float* __restrict__ x, float* __restrict__ xT,
                        const float* __restrict__ w_qkv, unsigned short* __restrict__ wbp) {
  __shared__ float tile[32][33];
  const int gb = blockIdx.x;
  if (gb < 2048) {
    int b   = gb >> 10;
    int rem = gb & 1023;
    int hw0 = (rem & 127) * 32;
    int c0  = (rem >> 7) * 32;
    int tx = threadIdx.x & 31, ty = threadIdx.x >> 5;   // 32x8
    const float* src = x + (size_t)b * CC * 4096;
    float* dst = xT + (size_t)b * 4096 * CC;
    #pragma unroll
    for (int i = ty; i < 32; i += 8)
      tile[i][tx] = src[(size_t)(c0 + i) * 4096 + hw0 + tx];
    __syncthreads();
    #pragma unroll
    for (int i = ty; i < 32; i += 8)
      dst[(size_t)(hw0 + i) * CC + c0 + tx] = tile[tx][i];
  } else {
    // wbp[((nt*8+ks)*64+lane)*8+i] = bf16(w_qkv[nt*16+(lane&15)][ks*32+(lane>>4)*8+i])
    int g = (gb - 2048) * 256 + threadIdx.x;      // 0..24575
    int lane = g & 63;
    int ks = (g >> 6) & 7;
    int nt = g >> 9;
    int n  = nt * 16 + (lane & 15);
    int k0 = ks * 32 + (lane >> 4) * 8;
    const float* src = w_qkv + (size_t)n * CC + k0;
    float4 lo = *(const float4*)(src);
    float4 hi = *(const float4*)(src + 4);
    unsigned short o[8] = { f2bf(lo.x), f2bf(lo.y), f2bf(lo.z), f2bf(lo.w),
                            f2bf(hi.x), f2bf(hi.y), f2bf(hi.z), f2bf(hi.w) };
    *(uint4*)(wbp + (size_t)g * 8) = *(uint4*)o;
  }
}

// ---------- K1: per-window sample + MFMA QKV GEMM -> qkv_ws (bf16, [win][r][j]) ----------
// Round-13: r11-proven structure restored (64-row padded spb, bfrag register
// double-buffer, bounds(256,3) — r12's DB removal re-serialized B loads,
// 70->87us). One isolated change: phase B batch-4 sampling (16 outstanding
// loads per wait, was 4 with depth-1 rotation).
__launch_bounds__(256, 3)
__global__ void k1_sample_qkv(const float* __restrict__ xT,
                              const float* __restrict__ polys,
                              const unsigned short* __restrict__ wbp,
                              const float* __restrict__ b_qkv,
                              unsigned short* __restrict__ qkv_ws) {
  __shared__ __align__(16) unsigned short spb[64 * SPB_LD];   // rows 49..63 zeroed
  __shared__ __align__(16) unsigned short Cwbuf[4][16 * CW_LD];
  __shared__ float co_x0[WS2], co_y0[WS2], co_wx[WS2], co_wy[WS2];
  const int tid = threadIdx.x;
  const int m = blockIdx.x;
  const int b = blockIdx.y;

  // Phase A: coords for the 49 rows of this window (grid scramble: n = m*49+r)
  if (tid < WS2) {
    int n = m * WS2 + tid;
    int q = n / (WS2 * NP);
    int p = (n / NP) % WS2;
    int a = n % NP;
    const float* pc = polys + (size_t)(b * QN + q) * 12;
    float al = (float)a * 0.2f;
    float py = pc[0];
    float px = pc[6];
    #pragma unroll
    for (int i = 1; i < 6; i++) { py = py * al + pc[i]; px = px * al + pc[6 + i]; }
    py = 2.0f * py - 1.0f;
    px = 2.0f * px - 1.0f;
    float gy = py + (2.0f * (-4.0f + (float)(p / 7) * (7.0f / 6.0f))) * (1.0f / 64.0f);
    float gx = px + (2.0f * (-4.0f + (float)(p % 7) * (7.0f / 6.0f))) * (1.0f / 64.0f);
    // NOTE the reference swap: fx from grid_y, fy from grid_x
    float fx = (gy + 1.0f) * 0.5f * 63.0f;
    float fy = (gx + 1.0f) * 0.5f * 63.0f;
    float x0 = floorf(fx), y0 = floorf(fy);
    co_x0[tid] = x0; co_y0[tid] = y0;
    co_wx[tid] = fx - x0; co_wy[tid] = fy - y0;
  }
  // zero pad rows 49..63
  {
    unsigned int* z = (unsigned int*)(spb + WS2 * SPB_LD);
    for (int i = tid; i < 15 * SPB_LD / 2; i += 256) z[i] = 0u;
  }
  __syncthreads();

  // Phase B: bilinear sampling, thread = channel, batch-4 rows (16 loads in flight)
  const float* xb = xT + (size_t)b * (4096 * CC);
  for (int bi = 0; bi < 12; bi++) {
    const int rbase = bi * 4;
    float vv[4][4], wxa[4], wya[4];
    #pragma unroll
    for (int k = 0; k < 4; k++) {
      int r = rbase + k;
      float x0 = co_x0[r], y0 = co_y0[r];
      wxa[k] = co_wx[r]; wya[k] = co_wy[r];
      float x1 = x0 + 1.0f, y1 = y0 + 1.0f;
      int xi0 = (int)fminf(fmaxf(x0, 0.0f), 63.0f);
      int yi0 = (int)fminf(fmaxf(y0, 0.0f), 63.0f);
      int xi1 = (int)fminf(fmaxf(x1, 0.0f), 63.0f);
      int yi1 = (int)fminf(fmaxf(y1, 0.0f), 63.0f);
      bool vx0 = (x0 >= 0.0f) && (x0 <= 63.0f);
      bool vx1 = (x1 >= 0.0f) && (x1 <= 63.0f);
      bool vy0 = (y0 >= 0.0f) && (y0 <= 63.0f);
      bool vy1 = (y1 >= 0.0f) && (y1 <= 63.0f);
      vv[k][0] = (vx0 && vy0) ? xb[(yi0 * 64 + xi0) * CC + tid] : 0.0f;
      vv[k][1] = (vx1 && vy0) ? xb[(yi0 * 64 + xi1) * CC + tid] : 0.0f;
      vv[k][2] = (vx0 && vy1) ? xb[(yi1 * 64 + xi0) * CC + tid] : 0.0f;
      vv[k][3] = (vx1 && vy1) ? xb[(yi1 * 64 + xi1) * CC + tid] : 0.0f;
    }
    #pragma unroll
    for (int k = 0; k < 4; k++) {
      int r = rbase + k;
      float wx = wxa[k], wy = wya[k];
      float s = vv[k][0] * (1.0f - wy) * (1.0f - wx) + vv[k][1] * (1.0f - wy) * wx
              + vv[k][2] * wy * (1.0f - wx) + vv[k][3] * wy * wx;
      spb[r * SPB_LD + tid] = f2bf(s);
    }
  }
  {  // tail row 48
    const int r = 48;
    float x0 = co_x0[r], y0 = co_y0[r];
    float wx = co_wx[r], wy = co_wy[r];
    float x1 = x0 + 1.0f, y1 = y0 + 1.0f;
    int xi0 = (int)fminf(fmaxf(x0, 0.0f), 63.0f);
    int yi0 = (int)fminf(fmaxf(y0, 0.0f), 63.0f);
    int xi1 = (int)fminf(fmaxf(x1, 0.0f), 63.0f);
    int yi1 = (int)fminf(fmaxf(y1, 0.0f), 63.0f);
    bool vx0 = (x0 >= 0.0f) && (x0 <= 63.0f);
    bool vx1 = (x1 >= 0.0f) && (x1 <= 63.0f);
    bool vy0 = (y0 >= 0.0f) && (y0 <= 63.0f);
    bool vy1 = (y1 >= 0.0f) && (y1 <= 63.0f);
    float v00 = (vx0 && vy0) ? xb[(yi0 * 64 + xi0) * CC + tid] : 0.0f;
    float v01 = (vx1 && vy0) ? xb[(yi0 * 64 + xi1) * CC + tid] : 0.0f;
    float v10 = (vx0 && vy1) ? xb[(yi1 * 64 + xi0) * CC + tid] : 0.0f;
    float v11 = (vx1 && vy1) ? xb[(yi1 * 64 + xi1) * CC + tid] : 0.0f;
    float s = v00 * (1.0f - wy) * (1.0f - wx) + v01 * (1.0f - wy) * wx
            + v10 * wy * (1.0f - wx) + v11 * wy * wx;
    spb[r * SPB_LD + tid] = f2bf(s);
  }
  __syncthreads();

  // Phase C: MFMA GEMM. Wave wv owns N-tiles [wv*12,+12) in 3 chunks of 4.
  const int lane = tid & 63;
  const int wv = tid >> 6;
  const int lm = lane & 15;
  const int lg = lane >> 4;
  unsigned short* qd = qkv_ws + (size_t)(b * NWIN + m) * QKV_SHORTS_PER_WIN;
  unsigned short* Cw = &Cwbuf[wv][0];

  for (int jc = 0; jc < 3; jc++) {
    const int nt0 = wv * 12 + jc * 4;
    const int ncol0 = nt0 * 16 + lm;
    f32x4 acc[4][4];
    #pragma unroll
    for (int j4 = 0; j4 < 4; j4++) {
      float bias = b_qkv[ncol0 + j4 * 16];
      #pragma unroll
      for (int mt = 0; mt < 4; mt++) acc[mt][j4] = (f32x4){bias, bias, bias, bias};
    }
    // register double-buffer for B fragments (r12 proved removal costs ~17us)
    bf16x8 bnx[4];
    #pragma unroll
    for (int j4 = 0; j4 < 4; j4++)
      bnx[j4] = *(const bf16x8*)(wbp + (size_t)(((nt0 + j4) * 8 + 0) * 64 + lane) * 8);
    #pragma unroll
    for (int ks = 0; ks < 8; ks++) {
      bf16x8 bc[4];
      #pragma unroll
      for (int j4 = 0; j4 < 4; j4++) bc[j4] = bnx[j4];
      if (ks < 7) {
        #pragma unroll
        for (int j4 = 0; j4 < 4; j4++)
          bnx[j4] = *(const bf16x8*)(wbp + (size_t)(((nt0 + j4) * 8 + ks + 1) * 64 + lane) * 8);
      }
      bf16x8 af[4];
      #pragma unroll
      for (int mt = 0; mt < 4; mt++)
        af[mt] = *(const bf16x8*)(spb + (mt * 16 + lm) * SPB_LD + ks * 32 + lg * 8);
      #pragma unroll
      for (int j4 = 0; j4 < 4; j4++)
        #pragma unroll
        for (int mt = 0; mt < 4; mt++)
          acc[mt][j4] = __builtin_amdgcn_mfma_f32_16x16x32_bf16(af[mt], bc[j4], acc[mt][j4], 0, 0, 0);
    }
    // per-mt 16-row assembly + full-line stores (8 lines per uint4 instr)
    const int cbase = nt0 * 16;
    #pragma unroll
    for (int mt = 0; mt < 4; mt++) {
      #pragma unroll
      for (int reg = 0; reg < 4; reg++) {
        int rr = lg * 4 + reg;   // row within tile
        #pragma unroll
        for (int j4 = 0; j4 < 4; j4++)
          Cw[rr * CW_LD + j4 * 16 + lm] = f2bf(acc[mt][j4][reg]);
      }
      int r0 = mt * 16;
      #pragma unroll
      for (int half = 0; half < 2; half++) {
        int idx = half * 64 + lane;
        int r16 = idx >> 3;       // 0..15
        int seg = idx & 7;
        int r = r0 + r16;
        if (r < WS2)
          *(uint4*)(qd + (size_t)r * 768 + cbase + seg * 8) =
              *(const uint4*)(Cw + r16 * CW_LD + seg * 8);
      }
    }
  }
}

// ---------- K2: MFMA windowed attention, wave-per-head (2 heads/wave) ----------
// r11 full-line O stores + r12 uint2 V staging with one-time Vt zeroing.
#define P_LD 72    // P row stride in shorts
#define V_LD 72    // Vt row stride in shorts
#define OW_LD 36   // O assembly row stride in floats
#define P_WAVE (WS2 * P_LD)          // 3528 shorts per wave
#define V_OFF  (4 * P_WAVE)          // 14112 shorts
#define V_WAVE (32 * V_LD)           // 2304 shorts per wave
__launch_bounds__(256, 3)
__global__ void k2_attn(const unsigned short* __restrict__ qkv_ws,
                        float* __restrict__ o_ws) {
  __shared__ __align__(16) unsigned short lds[V_OFF + 4 * V_WAVE];  // 46656 B
  const int tid = threadIdx.x;
  const int lane = tid & 63;
  const int wv = tid >> 6;
  const int lm = lane & 15;
  const int lg = lane >> 4;
  const int m = blockIdx.x;
  const int b = blockIdx.y;
  const unsigned short* wsrc = qkv_ws + (size_t)(b * NWIN + m) * QKV_SHORTS_PER_WIN;
  const float scale = 0.17677669529663687f;  // 1/sqrt(32)
  unsigned short* P  = lds + wv * P_WAVE;
  unsigned short* Vt = lds + V_OFF + wv * V_WAVE;
  float* Ow = (float*)P;   // O assembly reuses P region after PV (same-wave ds order)

  // zero Vt once (rows r>=49 must be 0; bf16-NaN garbage x P=0 would make NaN)
  {
    unsigned int* vz = (unsigned int*)Vt;
    #pragma unroll
    for (int i = 0; i < 18; i++) vz[i * 64 + lane] = 0u;
  }

  for (int hh = 0; hh < 2; hh++) {
    const int h = wv * 2 + hh;

    // Stage V^T: Vt[d][r] from wsrc[r*768+512+h*32+d], uint2 (4 shorts) per lane
    for (int i = 0; i < 7; i++) {
      int idx = i * 64 + lane;          // idx = r*8 + dg
      if (idx < WS2 * 8) {
        int r = idx >> 3;
        int d0 = (idx & 7) * 4;
        const unsigned short* pp = wsrc + (size_t)r * 768 + 512 + h * HDD + d0;
        uint2 u = *(const uint2*)pp;
        Vt[(d0 + 0) * V_LD + r] = (unsigned short)(u.x & 0xffffu);
        Vt[(d0 + 1) * V_LD + r] = (unsigned short)(u.x >> 16);
        Vt[(d0 + 2) * V_LD + r] = (unsigned short)(u.y & 0xffffu);
        Vt[(d0 + 3) * V_LD + r] = (unsigned short)(u.y >> 16);
      }
    }

    // Q/K fragments straight from global [r][j], row-clamped
    bf16x8 qf[4], kf[4];
    #pragma unroll
    for (int t = 0; t < 4; t++) {
      int r = t * 16 + lm; if (r > 48) r = 48;
      qf[t] = *(const bf16x8*)(wsrc + (size_t)r * 768 + h * HDD + lg * 8);
      kf[t] = *(const bf16x8*)(wsrc + (size_t)r * 768 + 256 + h * HDD + lg * 8);
    }

    // S = Q K^T
    f32x4 s[4][4];
    #pragma unroll
    for (int mt = 0; mt < 4; mt++)
      #pragma unroll
      for (int nt = 0; nt < 4; nt++) {
        s[mt][nt] = (f32x4){0.f, 0.f, 0.f, 0.f};
        s[mt][nt] = __builtin_amdgcn_mfma_f32_16x16x32_bf16(qf[mt], kf[nt], s[mt][nt], 0, 0, 0);
      }

    #pragma unroll
    for (int mt = 0; mt < 4; mt++)
      #pragma unroll
      for (int nt = 0; nt < 4; nt++) {
        bool badcol = (nt == 3) && (lm > 0);
        #pragma unroll
        for (int reg = 0; reg < 4; reg++)
          s[mt][nt][reg] = badcol ? -1e30f : s[mt][nt][reg] * scale;
      }

    // softmax over keys (pos_bias is per-row constant: cancels exactly)
    #pragma unroll
    for (int mt = 0; mt < 4; mt++) {
      #pragma unroll
      for (int reg = 0; reg < 4; reg++) {
        float mx = fmaxf(fmaxf(s[mt][0][reg], s[mt][1][reg]),
                         fmaxf(s[mt][2][reg], s[mt][3][reg]));
        #pragma unroll
        for (int off = 1; off < 16; off <<= 1) mx = fmaxf(mx, __shfl_xor(mx, off));
        float sum = 0.0f;
        #pragma unroll
        for (int nt = 0; nt < 4; nt++) {
          float e = __expf(s[mt][nt][reg] - mx);
          s[mt][nt][reg] = e;
          sum += e;
        }
        #pragma unroll
        for (int off = 1; off < 16; off <<= 1) sum += __shfl_xor(sum, off);
        float inv = 1.0f / sum;
        #pragma unroll
        for (int nt = 0; nt < 4; nt++) s[mt][nt][reg] *= inv;
      }
    }

    // P (bf16) -> LDS row-major [p][r2]
    #pragma unroll
    for (int mt = 0; mt < 4; mt++)
      #pragma unroll
      for (int nt = 0; nt < 4; nt++)
        #pragma unroll
        for (int reg = 0; reg < 4; reg++) {
          int p = mt * 16 + lg * 4 + reg;
          if (p < WS2) P[p * P_LD + nt * 16 + lm] = f2bf(s[mt][nt][reg]);
        }

    // O = P V
    f32x4 o[4][2];
    #pragma unroll
    for (int mt = 0; mt < 4; mt++)
      #pragma unroll
      for (int nt2 = 0; nt2 < 2; nt2++) o[mt][nt2] = (f32x4){0.f, 0.f, 0.f, 0.f};
    #pragma unroll
    for (int ks = 0; ks < 2; ks++) {
      bf16x8 vf[2];
      #pragma unroll
      for (int nt2 = 0; nt2 < 2; nt2++)
        vf[nt2] = *(const bf16x8*)(Vt + (nt2 * 16 + lm) * V_LD + ks * 32 + lg * 8);
      #pragma unroll
      for (int mt = 0; mt < 4; mt++) {
        bf16x8 af = *(const bf16x8*)(P + (mt * 16 + lm) * P_LD + ks * 32 + lg * 8);
        #pragma unroll
        for (int nt2 = 0; nt2 < 2; nt2++)
          o[mt][nt2] = __builtin_amdgcn_mfma_f32_16x16x32_bf16(af, vf[nt2], o[mt][nt2], 0, 0, 0);
      }
    }

    // O -> LDS assembly (P region dead after PV; same-wave ds program order)
    #pragma unroll
    for (int mt = 0; mt < 4; mt++)
      #pragma unroll
      for (int reg = 0; reg < 4; reg++) {
        int p = mt * 16 + lg * 4 + reg;
        if (p < WS2) {
          #pragma unroll
          for (int nt2 = 0; nt2 < 2; nt2++)
            Ow[p * OW_LD + nt2 * 16 + lm] = o[mt][nt2][reg];
        }
      }
    // full-line stores: 8 lanes x uint4 = one complete 128B line per row
    float* ob = o_ws + (size_t)b * O_PER_B + ((size_t)h * WS2 * NWIN + m) * HDD;
    for (int idx = lane; idx < WS2 * 8; idx += 64) {
      int p = idx >> 3, seg = idx & 7;
      *(uint4*)(ob + (size_t)p * (NWIN * HDD) + seg * 4) =
          *(const uint4*)(Ow + p * OW_LD + seg * 4);
    }
  }
}

// ---------- K3: conv (49-tap over p') + projection ----------
__global__ void k3_conv_proj(const float* __restrict__ o_ws,
                             const float* __restrict__ conv_w,
                             const float* __restrict__ conv_b,
                             const float* __restrict__ w_proj,
                             const float* __restrict__ b_proj,
                             float* __restrict__ out) {
  __shared__ float yv[CC];
  __shared__ float cw[WS2];
  const int tid = threadIdx.x;
  const int np = blockIdx.x;
  const int b = blockIdx.y;
  if (tid < WS2) cw[tid] = conv_w[tid];
  __syncthreads();
  const float* base = o_ws + (size_t)b * O_PER_B + (size_t)np * (WS2 * CC);
  float acc = conv_b[0];
  for (int p = 0; p < WS2; p++)
    acc += cw[p] * base[p * CC + tid];
  yv[tid] = acc;
  __syncthreads();
  const float4* y4 = (const float4*)yv;
  const float4* w4 = (const float4*)(w_proj + (size_t)tid * CC);
  float s = b_proj[tid];
  float s2 = 0.0f;
  #pragma unroll 8
  for (int c4 = 0; c4 < 64; c4++) {
    float4 a = y4[c4], wv2 = w4[c4];
    s2 += a.x * wv2.x + a.y * wv2.y + a.z * wv2.z + a.w * wv2.w;
  }
  out[((size_t)(b * NWIN + np)) * CC + tid] = s + s2;
}

extern "C" void kernel_launch(void* const* d_in, const int* in_sizes, int n_in,
                              void* d_out, int out_size, void* d_ws, size_t ws_size,
                              hipStream_t stream) {
  const float* x        = (const float*)d_in[0];
  const float* polys    = (const float*)d_in[1];
  const float* w_qkv    = (const float*)d_in[2];
  const float* b_qkv    = (const float*)d_in[3];
  const float* w_proj   = (const float*)d_in[4];
  const float* b_proj   = (const float*)d_in[5];
  const float* conv_w   = (const float*)d_in[6];
  const float* conv_b   = (const float*)d_in[7];
  float* out = (float*)d_out;

  char* ws = (char*)d_ws;
  float* xT = (float*)ws;
  unsigned short* wbp = (unsigned short*)(ws + XT_BYTES);
  unsigned short* qkv_ws = (unsigned short*)(ws + XT_BYTES + WB_BYTES);
  float* o_ws = (float*)(ws + XT_BYTES + WB_BYTES + QKV_BYTES);

  hipLaunchKernelGGL(k0_prep, dim3(2144), dim3(256), 0, stream, x, xT, w_qkv, wbp);
  hipLaunchKernelGGL(k1_sample_qkv, dim3(NWIN, B_), dim3(256), 0, stream,
                     xT, polys, wbp, b_qkv, qkv_ws);
  hipLaunchKernelGGL(k2_attn, dim3(NWIN, B_), dim3(256), 0, stream,
                     qkv_ws, o_ws);
  hipLaunchKernelGGL(k3_conv_proj, dim3(NWIN, B_), dim3(256), 0, stream,
                     o_ws, conv_w, conv_b, w_proj, b_proj, out);
}

// Round 14
// 200.861 us; speedup vs baseline: 1.2079x; 1.0636x over previous
//
#include <hip/hip_runtime.h>
#include <hip/hip_bf16.h>

// Problem constants
#define B_    2
#define QN    100
#define NP    6
#define WS2   49
#define CC    256
#define NHH   8
#define HDD   32
#define NWIN  600            // Q*Np windows per batch
#define O_PER_B 7526400      // NH*WS2*NWIN*HD

// ws layout (bytes): xT fp32 (+1KB zero page) | wbp bf16 [48][8][64][8] | qkv bf16 | O fp32
#define XT_BYTES   (8388608 + 1024)
#define ZABS       2097152                  // element index of the zero page in xT
#define WB_BYTES   393216
#define QKV_SHORTS_PER_WIN (WS2 * 768)      // 37632 shorts
#define QKV_BYTES  (1200 * WS2 * 768 * 2)   // 90316800

#define SPB_LD 264   // bf16 sp row stride (shorts)
#define CW_LD  72    // per-wave C line-assembly row stride (144B rows, 16B-aligned)

typedef __attribute__((ext_vector_type(8))) short bf16x8;
typedef __attribute__((ext_vector_type(4))) float f32x4;

__device__ __forceinline__ unsigned short f2bf(float f) {
  union { float f; unsigned int i; } v; v.f = f;
  unsigned int x = v.i;
  x += 0x7fffu + ((x >> 16) & 1u);   // round-to-nearest-even
  return (unsigned short)(x >> 16);
}

// ---------- K0: x-transpose (0..2047) + w_qkv pack (2048..2143) + zero page (2144) ----------
__global__ void k0_prep(const float* __restrict__ x, float* __restrict__ xT,
                        const float* __restrict__ w_qkv, unsigned short* __restrict__ wbp) {
  __shared__ float tile[32][33];
  const int gb = blockIdx.x;
  if (gb < 2048) {
    int b   = gb >> 10;
    int rem = gb & 1023;
    int hw0 = (rem & 127) * 32;
    int c0  = (rem >> 7) * 32;
    int tx = threadIdx.x & 31, ty = threadIdx.x >> 5;   // 32x8
    const float* src = x + (size_t)b * CC * 4096;
    float* dst = xT + (size_t)b * 4096 * CC;
    #pragma unroll
    for (int i = ty; i < 32; i += 8)
      tile[i][tx] = src[(size_t)(c0 + i) * 4096 + hw0 + tx];
    __syncthreads();
    #pragma unroll
    for (int i = ty; i < 32; i += 8)
      dst[(size_t)(hw0 + i) * CC + c0 + tx] = tile[tx][i];
  } else if (gb < 2144) {
    // wbp[((nt*8+ks)*64+lane)*8+i] = bf16(w_qkv[nt*16+(lane&15)][ks*32+(lane>>4)*8+i])
    int g = (gb - 2048) * 256 + threadIdx.x;      // 0..24575
    int lane = g & 63;
    int ks = (g >> 6) & 7;
    int nt = g >> 9;
    int n  = nt * 16 + (lane & 15);
    int k0 = ks * 32 + (lane >> 4) * 8;
    const float* src = w_qkv + (size_t)n * CC + k0;
    float4 lo = *(const float4*)(src);
    float4 hi = *(const float4*)(src + 4);
    unsigned short o[8] = { f2bf(lo.x), f2bf(lo.y), f2bf(lo.z), f2bf(lo.w),
                            f2bf(hi.x), f2bf(hi.y), f2bf(hi.z), f2bf(hi.w) };
    *(uint4*)(wbp + (size_t)g * 8) = *(uint4*)o;
  } else {
    xT[ZABS + threadIdx.x] = 0.0f;   // zero page for invalid bilinear corners
  }
}

// ---------- K1: per-window sample + MFMA QKV GEMM -> qkv_ws (bf16, [win][r][j]) ----------
// Round-14 (on the r13 66us config): phase-A precompute of per-row-uniform
// work — 4 absolute offsets (invalid corners -> zero page; kills all clamps
// and cndmasks in the hot loop) + 4 pre-multiplied weights. Phase-B per row:
// int4/float4 LDS broadcast + 4 adds + 4 loads + 4 FMA + f2bf (~12 VALU, was ~30).
__launch_bounds__(256, 3)
__global__ void k1_sample_qkv(const float* __restrict__ xT,
                              const float* __restrict__ polys,
                              const unsigned short* __restrict__ wbp,
                              const float* __restrict__ b_qkv,
                              unsigned short* __restrict__ qkv_ws) {
  __shared__ __align__(16) unsigned short spb[64 * SPB_LD];   // rows 49..63 zeroed
  __shared__ __align__(16) unsigned short Cwbuf[4][16 * CW_LD];
  __shared__ __align__(16) int   co_off[WS2][4];
  __shared__ __align__(16) float co_w[WS2][4];
  const int tid = threadIdx.x;
  const int m = blockIdx.x;
  const int b = blockIdx.y;

  // Phase A: per-row offsets + weights (grid scramble: n = m*49+r)
  if (tid < WS2) {
    int n = m * WS2 + tid;
    int q = n / (WS2 * NP);
    int p = (n / NP) % WS2;
    int a = n % NP;
    const float* pc = polys + (size_t)(b * QN + q) * 12;
    float al = (float)a * 0.2f;
    float py = pc[0];
    float px = pc[6];
    #pragma unroll
    for (int i = 1; i < 6; i++) { py = py * al + pc[i]; px = px * al + pc[6 + i]; }
    py = 2.0f * py - 1.0f;
    px = 2.0f * px - 1.0f;
    float gy = py + (2.0f * (-4.0f + (float)(p / 7) * (7.0f / 6.0f))) * (1.0f / 64.0f);
    float gx = px + (2.0f * (-4.0f + (float)(p % 7) * (7.0f / 6.0f))) * (1.0f / 64.0f);
    // NOTE the reference swap: fx from grid_y, fy from grid_x
    float fx = (gy + 1.0f) * 0.5f * 63.0f;
    float fy = (gx + 1.0f) * 0.5f * 63.0f;
    float x0 = floorf(fx), y0 = floorf(fy);
    float wx = fx - x0, wy = fy - y0;
    float x1 = x0 + 1.0f, y1 = y0 + 1.0f;
    int xi0 = (int)fminf(fmaxf(x0, 0.0f), 63.0f);
    int yi0 = (int)fminf(fmaxf(y0, 0.0f), 63.0f);
    int xi1 = (int)fminf(fmaxf(x1, 0.0f), 63.0f);
    int yi1 = (int)fminf(fmaxf(y1, 0.0f), 63.0f);
    bool vx0 = (x0 >= 0.0f) && (x0 <= 63.0f);
    bool vx1 = (x1 >= 0.0f) && (x1 <= 63.0f);
    bool vy0 = (y0 >= 0.0f) && (y0 <= 63.0f);
    bool vy1 = (y1 >= 0.0f) && (y1 <= 63.0f);
    const int bb = b * 4096;
    co_off[tid][0] = (vx0 && vy0) ? (bb + yi0 * 64 + xi0) * CC : ZABS;
    co_off[tid][1] = (vx1 && vy0) ? (bb + yi0 * 64 + xi1) * CC : ZABS;
    co_off[tid][2] = (vx0 && vy1) ? (bb + yi1 * 64 + xi0) * CC : ZABS;
    co_off[tid][3] = (vx1 && vy1) ? (bb + yi1 * 64 + xi1) * CC : ZABS;
    co_w[tid][0] = (1.0f - wy) * (1.0f - wx);
    co_w[tid][1] = (1.0f - wy) * wx;
    co_w[tid][2] = wy * (1.0f - wx);
    co_w[tid][3] = wy * wx;
  }
  // zero pad rows 49..63
  {
    unsigned int* z = (unsigned int*)(spb + WS2 * SPB_LD);
    for (int i = tid; i < 15 * SPB_LD / 2; i += 256) z[i] = 0u;
  }
  __syncthreads();

  // Phase B: bilinear sampling, thread = channel, batch-4 rows (16 loads in flight)
  for (int bi = 0; bi < 12; bi++) {
    const int rbase = bi * 4;
    float vv[4][4];
    #pragma unroll
    for (int k = 0; k < 4; k++) {
      int r = rbase + k;
      int4 off = *(const int4*)&co_off[r][0];
      vv[k][0] = xT[off.x + tid];
      vv[k][1] = xT[off.y + tid];
      vv[k][2] = xT[off.z + tid];
      vv[k][3] = xT[off.w + tid];
    }
    #pragma unroll
    for (int k = 0; k < 4; k++) {
      int r = rbase + k;
      float4 w = *(const float4*)&co_w[r][0];
      float s = vv[k][0] * w.x + vv[k][1] * w.y + vv[k][2] * w.z + vv[k][3] * w.w;
      spb[r * SPB_LD + tid] = f2bf(s);
    }
  }
  {  // tail row 48
    int4 off = *(const int4*)&co_off[48][0];
    float4 w = *(const float4*)&co_w[48][0];
    float s = xT[off.x + tid] * w.x + xT[off.y + tid] * w.y
            + xT[off.z + tid] * w.z + xT[off.w + tid] * w.w;
    spb[48 * SPB_LD + tid] = f2bf(s);
  }
  __syncthreads();

  // Phase C: MFMA GEMM. Wave wv owns N-tiles [wv*12,+12) in 3 chunks of 4.
  const int lane = tid & 63;
  const int wv = tid >> 6;
  const int lm = lane & 15;
  const int lg = lane >> 4;
  unsigned short* qd = qkv_ws + (size_t)(b * NWIN + m) * QKV_SHORTS_PER_WIN;
  unsigned short* Cw = &Cwbuf[wv][0];

  for (int jc = 0; jc < 3; jc++) {
    const int nt0 = wv * 12 + jc * 4;
    const int ncol0 = nt0 * 16 + lm;
    f32x4 acc[4][4];
    #pragma unroll
    for (int j4 = 0; j4 < 4; j4++) {
      float bias = b_qkv[ncol0 + j4 * 16];
      #pragma unroll
      for (int mt = 0; mt < 4; mt++) acc[mt][j4] = (f32x4){bias, bias, bias, bias};
    }
    // register double-buffer for B fragments (r12 proved removal costs ~17us)
    bf16x8 bnx[4];
    #pragma unroll
    for (int j4 = 0; j4 < 4; j4++)
      bnx[j4] = *(const bf16x8*)(wbp + (size_t)(((nt0 + j4) * 8 + 0) * 64 + lane) * 8);
    #pragma unroll
    for (int ks = 0; ks < 8; ks++) {
      bf16x8 bc[4];
      #pragma unroll
      for (int j4 = 0; j4 < 4; j4++) bc[j4] = bnx[j4];
      if (ks < 7) {
        #pragma unroll
        for (int j4 = 0; j4 < 4; j4++)
          bnx[j4] = *(const bf16x8*)(wbp + (size_t)(((nt0 + j4) * 8 + ks + 1) * 64 + lane) * 8);
      }
      bf16x8 af[4];
      #pragma unroll
      for (int mt = 0; mt < 4; mt++)
        af[mt] = *(const bf16x8*)(spb + (mt * 16 + lm) * SPB_LD + ks * 32 + lg * 8);
      #pragma unroll
      for (int j4 = 0; j4 < 4; j4++)
        #pragma unroll
        for (int mt = 0; mt < 4; mt++)
          acc[mt][j4] = __builtin_amdgcn_mfma_f32_16x16x32_bf16(af[mt], bc[j4], acc[mt][j4], 0, 0, 0);
    }
    // per-mt 16-row assembly + full-line stores (8 lines per uint4 instr)
    const int cbase = nt0 * 16;
    #pragma unroll
    for (int mt = 0; mt < 4; mt++) {
      #pragma unroll
      for (int reg = 0; reg < 4; reg++) {
        int rr = lg * 4 + reg;   // row within tile
        #pragma unroll
        for (int j4 = 0; j4 < 4; j4++)
          Cw[rr * CW_LD + j4 * 16 + lm] = f2bf(acc[mt][j4][reg]);
      }
      int r0 = mt * 16;
      #pragma unroll
      for (int half = 0; half < 2; half++) {
        int idx = half * 64 + lane;
        int r16 = idx >> 3;       // 0..15
        int seg = idx & 7;
        int r = r0 + r16;
        if (r < WS2)
          *(uint4*)(qd + (size_t)r * 768 + cbase + seg * 8) =
              *(const uint4*)(Cw + r16 * CW_LD + seg * 8);
      }
    }
  }
}

// ---------- K2: MFMA windowed attention, wave-per-head (2 heads/wave) ----------
// r11 full-line O stores + r12 uint2 V staging with one-time Vt zeroing.
#define P_LD 72    // P row stride in shorts
#define V_LD 72    // Vt row stride in shorts
#define OW_LD 36   // O assembly row stride in floats
#define P_WAVE (WS2 * P_LD)          // 3528 shorts per wave
#define V_OFF  (4 * P_WAVE)          // 14112 shorts
#define V_WAVE (32 * V_LD)           // 2304 shorts per wave
__launch_bounds__(256, 3)
__global__ void k2_attn(const unsigned short* __restrict__ qkv_ws,
                        float* __restrict__ o_ws) {
  __shared__ __align__(16) unsigned short lds[V_OFF + 4 * V_WAVE];  // 46656 B
  const int tid = threadIdx.x;
  const int lane = tid & 63;
  const int wv = tid >> 6;
  const int lm = lane & 15;
  const int lg = lane >> 4;
  const int m = blockIdx.x;
  const int b = blockIdx.y;
  const unsigned short* wsrc = qkv_ws + (size_t)(b * NWIN + m) * QKV_SHORTS_PER_WIN;
  const float scale = 0.17677669529663687f;  // 1/sqrt(32)
  unsigned short* P  = lds + wv * P_WAVE;
  unsigned short* Vt = lds + V_OFF + wv * V_WAVE;
  float* Ow = (float*)P;   // O assembly reuses P region after PV (same-wave ds order)

  // zero Vt once (rows r>=49 must be 0; bf16-NaN garbage x P=0 would make NaN)
  {
    unsigned int* vz = (unsigned int*)Vt;
    #pragma unroll
    for (int i = 0; i < 18; i++) vz[i * 64 + lane] = 0u;
  }

  for (int hh = 0; hh < 2; hh++) {
    const int h = wv * 2 + hh;

    // Stage V^T: Vt[d][r] from wsrc[r*768+512+h*32+d], uint2 (4 shorts) per lane
    for (int i = 0; i < 7; i++) {
      int idx = i * 64 + lane;          // idx = r*8 + dg
      if (idx < WS2 * 8) {
        int r = idx >> 3;
        int d0 = (idx & 7) * 4;
        const unsigned short* pp = wsrc + (size_t)r * 768 + 512 + h * HDD + d0;
        uint2 u = *(const uint2*)pp;
        Vt[(d0 + 0) * V_LD + r] = (unsigned short)(u.x & 0xffffu);
        Vt[(d0 + 1) * V_LD + r] = (unsigned short)(u.x >> 16);
        Vt[(d0 + 2) * V_LD + r] = (unsigned short)(u.y & 0xffffu);
        Vt[(d0 + 3) * V_LD + r] = (unsigned short)(u.y >> 16);
      }
    }

    // Q/K fragments straight from global [r][j], row-clamped
    bf16x8 qf[4], kf[4];
    #pragma unroll
    for (int t = 0; t < 4; t++) {
      int r = t * 16 + lm; if (r > 48) r = 48;
      qf[t] = *(const bf16x8*)(wsrc + (size_t)r * 768 + h * HDD + lg * 8);
      kf[t] = *(const bf16x8*)(wsrc + (size_t)r * 768 + 256 + h * HDD + lg * 8);
    }

    // S = Q K^T
    f32x4 s[4][4];
    #pragma unroll
    for (int mt = 0; mt < 4; mt++)
      #pragma unroll
      for (int nt = 0; nt < 4; nt++) {
        s[mt][nt] = (f32x4){0.f, 0.f, 0.f, 0.f};
        s[mt][nt] = __builtin_amdgcn_mfma_f32_16x16x32_bf16(qf[mt], kf[nt], s[mt][nt], 0, 0, 0);
      }

    #pragma unroll
    for (int mt = 0; mt < 4; mt++)
      #pragma unroll
      for (int nt = 0; nt < 4; nt++) {
        bool badcol = (nt == 3) && (lm > 0);
        #pragma unroll
        for (int reg = 0; reg < 4; reg++)
          s[mt][nt][reg] = badcol ? -1e30f : s[mt][nt][reg] * scale;
      }

    // softmax over keys (pos_bias is per-row constant: cancels exactly)
    #pragma unroll
    for (int mt = 0; mt < 4; mt++) {
      #pragma unroll
      for (int reg = 0; reg < 4; reg++) {
        float mx = fmaxf(fmaxf(s[mt][0][reg], s[mt][1][reg]),
                         fmaxf(s[mt][2][reg], s[mt][3][reg]));
        #pragma unroll
        for (int off = 1; off < 16; off <<= 1) mx = fmaxf(mx, __shfl_xor(mx, off));
        float sum = 0.0f;
        #pragma unroll
        for (int nt = 0; nt < 4; nt++) {
          float e = __expf(s[mt][nt][reg] - mx);
          s[mt][nt][reg] = e;
          sum += e;
        }
        #pragma unroll
        for (int off = 1; off < 16; off <<= 1) sum += __shfl_xor(sum, off);
        float inv = 1.0f / sum;
        #pragma unroll
        for (int nt = 0; nt < 4; nt++) s[mt][nt][reg] *= inv;
      }
    }

    // P (bf16) -> LDS row-major [p][r2]
    #pragma unroll
    for (int mt = 0; mt < 4; mt++)
      #pragma unroll
      for (int nt = 0; nt < 4; nt++)
        #pragma unroll
        for (int reg = 0; reg < 4; reg++) {
          int p = mt * 16 + lg * 4 + reg;
          if (p < WS2) P[p * P_LD + nt * 16 + lm] = f2bf(s[mt][nt][reg]);
        }

    // O = P V
    f32x4 o[4][2];
    #pragma unroll
    for (int mt = 0; mt < 4; mt++)
      #pragma unroll
      for (int nt2 = 0; nt2 < 2; nt2++) o[mt][nt2] = (f32x4){0.f, 0.f, 0.f, 0.f};
    #pragma unroll
    for (int ks = 0; ks < 2; ks++) {
      bf16x8 vf[2];
      #pragma unroll
      for (int nt2 = 0; nt2 < 2; nt2++)
        vf[nt2] = *(const bf16x8*)(Vt + (nt2 * 16 + lm) * V_LD + ks * 32 + lg * 8);
      #pragma unroll
      for (int mt = 0; mt < 4; mt++) {
        bf16x8 af = *(const bf16x8*)(P + (mt * 16 + lm) * P_LD + ks * 32 + lg * 8);
        #pragma unroll
        for (int nt2 = 0; nt2 < 2; nt2++)
          o[mt][nt2] = __builtin_amdgcn_mfma_f32_16x16x32_bf16(af, vf[nt2], o[mt][nt2], 0, 0, 0);
      }
    }

    // O -> LDS assembly (P region dead after PV; same-wave ds program order)
    #pragma unroll
    for (int mt = 0; mt < 4; mt++)
      #pragma unroll
      for (int reg = 0; reg < 4; reg++) {
        int p = mt * 16 + lg * 4 + reg;
        if (p < WS2) {
          #pragma unroll
          for (int nt2 = 0; nt2 < 2; nt2++)
            Ow[p * OW_LD + nt2 * 16 + lm] = o[mt][nt2][reg];
        }
      }
    // full-line stores: 8 lanes x uint4 = one complete 128B line per row
    float* ob = o_ws + (size_t)b * O_PER_B + ((size_t)h * WS2 * NWIN + m) * HDD;
    for (int idx = lane; idx < WS2 * 8; idx += 64) {
      int p = idx >> 3, seg = idx & 7;
      *(uint4*)(ob + (size_t)p * (NWIN * HDD) + seg * 4) =
          *(const uint4*)(Ow + p * OW_LD + seg * 4);
    }
  }
}

// ---------- K3: conv (49-tap over p') + projection ----------
__global__ void k3_conv_proj(const float* __restrict__ o_ws,
                             const float* __restrict__ conv_w,
                             const float* __restrict__ conv_b,
                             const float* __restrict__ w_proj,
                             const float* __restrict__ b_proj,
                             float* __restrict__ out) {
  __shared__ float yv[CC];
  __shared__ float cw[WS2];
  const int tid = threadIdx.x;
  const int np = blockIdx.x;
  const int b = blockIdx.y;
  if (tid < WS2) cw[tid] = conv_w[tid];
  __syncthreads();
  const float* base = o_ws + (size_t)b * O_PER_B + (size_t)np * (WS2 * CC);
  float acc = conv_b[0];
  for (int p = 0; p < WS2; p++)
    acc += cw[p] * base[p * CC + tid];
  yv[tid] = acc;
  __syncthreads();
  const float4* y4 = (const float4*)yv;
  const float4* w4 = (const float4*)(w_proj + (size_t)tid * CC);
  float s = b_proj[tid];
  float s2 = 0.0f;
  #pragma unroll 8
  for (int c4 = 0; c4 < 64; c4++) {
    float4 a = y4[c4], wv2 = w4[c4];
    s2 += a.x * wv2.x + a.y * wv2.y + a.z * wv2.z + a.w * wv2.w;
  }
  out[((size_t)(b * NWIN + np)) * CC + tid] = s + s2;
}

extern "C" void kernel_launch(void* const* d_in, const int* in_sizes, int n_in,
                              void* d_out, int out_size, void* d_ws, size_t ws_size,
                              hipStream_t stream) {
  const float* x        = (const float*)d_in[0];
  const float* polys    = (const float*)d_in[1];
  const float* w_qkv    = (const float*)d_in[2];
  const float* b_qkv    = (const float*)d_in[3];
  const float* w_proj   = (const float*)d_in[4];
  const float* b_proj   = (const float*)d_in[5];
  const float* conv_w   = (const float*)d_in[6];
  const float* conv_b   = (const float*)d_in[7];
  float* out = (float*)d_out;

  char* ws = (char*)d_ws;
  float* xT = (float*)ws;
  unsigned short* wbp = (unsigned short*)(ws + XT_BYTES);
  unsigned short* qkv_ws = (unsigned short*)(ws + XT_BYTES + WB_BYTES);
  float* o_ws = (float*)(ws + XT_BYTES + WB_BYTES + QKV_BYTES);

  hipLaunchKernelGGL(k0_prep, dim3(2145), dim3(256), 0, stream, x, xT, w_qkv, wbp);
  hipLaunchKernelGGL(k1_sample_qkv, dim3(NWIN, B_), dim3(256), 0, stream,
                     xT, polys, wbp, b_qkv, qkv_ws);
  hipLaunchKernelGGL(k2_attn, dim3(NWIN, B_), dim3(256), 0, stream,
                     qkv_ws, o_ws);
  hipLaunchKernelGGL(k3_conv_proj, dim3(NWIN, B_), dim3(256), 0, stream,
                     o_ws, conv_w, conv_b, w_proj, b_proj, out);
}

// Round 15
// 194.803 us; speedup vs baseline: 1.2455x; 1.0311x over previous
//
#include <hip/hip_runtime.h>
#include <hip/hip_bf16.h>

// Problem constants
#define B_    2
#define QN    100
#define NP    6
#define WS2   49
#define CC    256
#define NHH   8
#define HDD   32
#define NWIN  600            // Q*Np windows per batch
#define O_PER_B 7526400      // NH*WS2*NWIN*HD

// ws layout (bytes): xT fp32 (+1KB zero page) | wbp bf16 [48][8][64][8] | qkv bf16 | O fp32
#define XT_BYTES   (8388608 + 1024)
#define ZABS       2097152                  // element index of the zero page in xT
#define WB_BYTES   393216
#define QKV_SHORTS_PER_WIN (WS2 * 768)      // 37632 shorts
#define QKV_BYTES  (1200 * WS2 * 768 * 2)   // 90316800

#define SPB_LD 264   // bf16 sp row stride (shorts)
#define CW_LD  72    // per-wave C line-assembly row stride (144B rows, 16B-aligned)

typedef __attribute__((ext_vector_type(8))) short bf16x8;
typedef __attribute__((ext_vector_type(4))) float f32x4;

__device__ __forceinline__ unsigned short f2bf(float f) {
  union { float f; unsigned int i; } v; v.f = f;
  unsigned int x = v.i;
  x += 0x7fffu + ((x >> 16) & 1u);   // round-to-nearest-even
  return (unsigned short)(x >> 16);
}

// ---------- K0: x-transpose (0..2047) + w_qkv pack (2048..2143) + zero page (2144) ----------
__global__ void k0_prep(const float* __restrict__ x, float* __restrict__ xT,
                        const float* __restrict__ w_qkv, unsigned short* __restrict__ wbp) {
  __shared__ float tile[32][33];
  const int gb = blockIdx.x;
  if (gb < 2048) {
    int b   = gb >> 10;
    int rem = gb & 1023;
    int hw0 = (rem & 127) * 32;
    int c0  = (rem >> 7) * 32;
    int tx = threadIdx.x & 31, ty = threadIdx.x >> 5;   // 32x8
    const float* src = x + (size_t)b * CC * 4096;
    float* dst = xT + (size_t)b * 4096 * CC;
    #pragma unroll
    for (int i = ty; i < 32; i += 8)
      tile[i][tx] = src[(size_t)(c0 + i) * 4096 + hw0 + tx];
    __syncthreads();
    #pragma unroll
    for (int i = ty; i < 32; i += 8)
      dst[(size_t)(hw0 + i) * CC + c0 + tx] = tile[tx][i];
  } else if (gb < 2144) {
    int g = (gb - 2048) * 256 + threadIdx.x;      // 0..24575
    int lane = g & 63;
    int ks = (g >> 6) & 7;
    int nt = g >> 9;
    int n  = nt * 16 + (lane & 15);
    int k0 = ks * 32 + (lane >> 4) * 8;
    const float* src = w_qkv + (size_t)n * CC + k0;
    float4 lo = *(const float4*)(src);
    float4 hi = *(const float4*)(src + 4);
    unsigned short o[8] = { f2bf(lo.x), f2bf(lo.y), f2bf(lo.z), f2bf(lo.w),
                            f2bf(hi.x), f2bf(hi.y), f2bf(hi.z), f2bf(hi.w) };
    *(uint4*)(wbp + (size_t)g * 8) = *(uint4*)o;
  } else {
    xT[ZABS + threadIdx.x] = 0.0f;   // zero page for invalid bilinear corners
  }
}

// ---------- K1: per-window sample + MFMA QKV GEMM -> qkv_ws (bf16, [win][r][j]) ----------
// (r14-proven: phase-A uniform-work precompute + zero page, batch-4 sampling,
// bfrag register double-buffer, 16-row Cw full-line stores.)
__launch_bounds__(256, 3)
__global__ void k1_sample_qkv(const float* __restrict__ xT,
                              const float* __restrict__ polys,
                              const unsigned short* __restrict__ wbp,
                              const float* __restrict__ b_qkv,
                              unsigned short* __restrict__ qkv_ws) {
  __shared__ __align__(16) unsigned short spb[64 * SPB_LD];   // rows 49..63 zeroed
  __shared__ __align__(16) unsigned short Cwbuf[4][16 * CW_LD];
  __shared__ __align__(16) int   co_off[WS2][4];
  __shared__ __align__(16) float co_w[WS2][4];
  const int tid = threadIdx.x;
  const int m = blockIdx.x;
  const int b = blockIdx.y;

  // Phase A: per-row offsets + weights (grid scramble: n = m*49+r)
  if (tid < WS2) {
    int n = m * WS2 + tid;
    int q = n / (WS2 * NP);
    int p = (n / NP) % WS2;
    int a = n % NP;
    const float* pc = polys + (size_t)(b * QN + q) * 12;
    float al = (float)a * 0.2f;
    float py = pc[0];
    float px = pc[6];
    #pragma unroll
    for (int i = 1; i < 6; i++) { py = py * al + pc[i]; px = px * al + pc[6 + i]; }
    py = 2.0f * py - 1.0f;
    px = 2.0f * px - 1.0f;
    float gy = py + (2.0f * (-4.0f + (float)(p / 7) * (7.0f / 6.0f))) * (1.0f / 64.0f);
    float gx = px + (2.0f * (-4.0f + (float)(p % 7) * (7.0f / 6.0f))) * (1.0f / 64.0f);
    // NOTE the reference swap: fx from grid_y, fy from grid_x
    float fx = (gy + 1.0f) * 0.5f * 63.0f;
    float fy = (gx + 1.0f) * 0.5f * 63.0f;
    float x0 = floorf(fx), y0 = floorf(fy);
    float wx = fx - x0, wy = fy - y0;
    float x1 = x0 + 1.0f, y1 = y0 + 1.0f;
    int xi0 = (int)fminf(fmaxf(x0, 0.0f), 63.0f);
    int yi0 = (int)fminf(fmaxf(y0, 0.0f), 63.0f);
    int xi1 = (int)fminf(fmaxf(x1, 0.0f), 63.0f);
    int yi1 = (int)fminf(fmaxf(y1, 0.0f), 63.0f);
    bool vx0 = (x0 >= 0.0f) && (x0 <= 63.0f);
    bool vx1 = (x1 >= 0.0f) && (x1 <= 63.0f);
    bool vy0 = (y0 >= 0.0f) && (y0 <= 63.0f);
    bool vy1 = (y1 >= 0.0f) && (y1 <= 63.0f);
    const int bb = b * 4096;
    co_off[tid][0] = (vx0 && vy0) ? (bb + yi0 * 64 + xi0) * CC : ZABS;
    co_off[tid][1] = (vx1 && vy0) ? (bb + yi0 * 64 + xi1) * CC : ZABS;
    co_off[tid][2] = (vx0 && vy1) ? (bb + yi1 * 64 + xi0) * CC : ZABS;
    co_off[tid][3] = (vx1 && vy1) ? (bb + yi1 * 64 + xi1) * CC : ZABS;
    co_w[tid][0] = (1.0f - wy) * (1.0f - wx);
    co_w[tid][1] = (1.0f - wy) * wx;
    co_w[tid][2] = wy * (1.0f - wx);
    co_w[tid][3] = wy * wx;
  }
  // zero pad rows 49..63
  {
    unsigned int* z = (unsigned int*)(spb + WS2 * SPB_LD);
    for (int i = tid; i < 15 * SPB_LD / 2; i += 256) z[i] = 0u;
  }
  __syncthreads();

  // Phase B: bilinear sampling, thread = channel, batch-4 rows (16 loads in flight)
  for (int bi = 0; bi < 12; bi++) {
    const int rbase = bi * 4;
    float vv[4][4];
    #pragma unroll
    for (int k = 0; k < 4; k++) {
      int r = rbase + k;
      int4 off = *(const int4*)&co_off[r][0];
      vv[k][0] = xT[off.x + tid];
      vv[k][1] = xT[off.y + tid];
      vv[k][2] = xT[off.z + tid];
      vv[k][3] = xT[off.w + tid];
    }
    #pragma unroll
    for (int k = 0; k < 4; k++) {
      int r = rbase + k;
      float4 w = *(const float4*)&co_w[r][0];
      float s = vv[k][0] * w.x + vv[k][1] * w.y + vv[k][2] * w.z + vv[k][3] * w.w;
      spb[r * SPB_LD + tid] = f2bf(s);
    }
  }
  {  // tail row 48
    int4 off = *(const int4*)&co_off[48][0];
    float4 w = *(const float4*)&co_w[48][0];
    float s = xT[off.x + tid] * w.x + xT[off.y + tid] * w.y
            + xT[off.z + tid] * w.z + xT[off.w + tid] * w.w;
    spb[48 * SPB_LD + tid] = f2bf(s);
  }
  __syncthreads();

  // Phase C: MFMA GEMM. Wave wv owns N-tiles [wv*12,+12) in 3 chunks of 4.
  const int lane = tid & 63;
  const int wv = tid >> 6;
  const int lm = lane & 15;
  const int lg = lane >> 4;
  unsigned short* qd = qkv_ws + (size_t)(b * NWIN + m) * QKV_SHORTS_PER_WIN;
  unsigned short* Cw = &Cwbuf[wv][0];

  for (int jc = 0; jc < 3; jc++) {
    const int nt0 = wv * 12 + jc * 4;
    const int ncol0 = nt0 * 16 + lm;
    f32x4 acc[4][4];
    #pragma unroll
    for (int j4 = 0; j4 < 4; j4++) {
      float bias = b_qkv[ncol0 + j4 * 16];
      #pragma unroll
      for (int mt = 0; mt < 4; mt++) acc[mt][j4] = (f32x4){bias, bias, bias, bias};
    }
    // register double-buffer for B fragments (r12 proved removal costs ~17us)
    bf16x8 bnx[4];
    #pragma unroll
    for (int j4 = 0; j4 < 4; j4++)
      bnx[j4] = *(const bf16x8*)(wbp + (size_t)(((nt0 + j4) * 8 + 0) * 64 + lane) * 8);
    #pragma unroll
    for (int ks = 0; ks < 8; ks++) {
      bf16x8 bc[4];
      #pragma unroll
      for (int j4 = 0; j4 < 4; j4++) bc[j4] = bnx[j4];
      if (ks < 7) {
        #pragma unroll
        for (int j4 = 0; j4 < 4; j4++)
          bnx[j4] = *(const bf16x8*)(wbp + (size_t)(((nt0 + j4) * 8 + ks + 1) * 64 + lane) * 8);
      }
      bf16x8 af[4];
      #pragma unroll
      for (int mt = 0; mt < 4; mt++)
        af[mt] = *(const bf16x8*)(spb + (mt * 16 + lm) * SPB_LD + ks * 32 + lg * 8);
      #pragma unroll
      for (int j4 = 0; j4 < 4; j4++)
        #pragma unroll
        for (int mt = 0; mt < 4; mt++)
          acc[mt][j4] = __builtin_amdgcn_mfma_f32_16x16x32_bf16(af[mt], bc[j4], acc[mt][j4], 0, 0, 0);
    }
    // per-mt 16-row assembly + full-line stores (8 lines per uint4 instr)
    const int cbase = nt0 * 16;
    #pragma unroll
    for (int mt = 0; mt < 4; mt++) {
      #pragma unroll
      for (int reg = 0; reg < 4; reg++) {
        int rr = lg * 4 + reg;   // row within tile
        #pragma unroll
        for (int j4 = 0; j4 < 4; j4++)
          Cw[rr * CW_LD + j4 * 16 + lm] = f2bf(acc[mt][j4][reg]);
      }
      int r0 = mt * 16;
      #pragma unroll
      for (int half = 0; half < 2; half++) {
        int idx = half * 64 + lane;
        int r16 = idx >> 3;       // 0..15
        int seg = idx & 7;
        int r = r0 + r16;
        if (r < WS2)
          *(uint4*)(qd + (size_t)r * 768 + cbase + seg * 8) =
              *(const uint4*)(Cw + r16 * CW_LD + seg * 8);
      }
    }
  }
}

// ---------- K2: MFMA windowed attention, wave-per-head-pair, two-head pipeline ----------
// Round-15: MLP was the limiter (11 loads/wave in flight, 2.94 TB/s at ~900cyc
// qkv HBM latency). Pipeline: V(h0) uint4 loads -> Q/K BOTH heads (16 loads)
// -> unpack V(h0) -> S(h0) -> issue V(h1) loads -> finish h0 -> unpack V(h1)
// -> h1. ~24KB/wave in flight (2x).
#define P_LD 72    // P row stride in shorts
#define V_LD 72    // Vt row stride in shorts
#define OW_LD 36   // O assembly row stride in floats
#define P_WAVE (WS2 * P_LD)          // 3528 shorts per wave
#define V_OFF  (4 * P_WAVE)          // 14112 shorts
#define V_WAVE (32 * V_LD)           // 2304 shorts per wave

__device__ __forceinline__ void attn_head(
    const bf16x8 qf[4], const bf16x8 kf[4],
    unsigned short* P, unsigned short* Vt, float* Ow, float* ob,
    int lane, int lm, int lg) {
  const float scale = 0.17677669529663687f;  // 1/sqrt(32)
  // S = Q K^T
  f32x4 s[4][4];
  #pragma unroll
  for (int mt = 0; mt < 4; mt++)
    #pragma unroll
    for (int nt = 0; nt < 4; nt++) {
      s[mt][nt] = (f32x4){0.f, 0.f, 0.f, 0.f};
      s[mt][nt] = __builtin_amdgcn_mfma_f32_16x16x32_bf16(qf[mt], kf[nt], s[mt][nt], 0, 0, 0);
    }
  #pragma unroll
  for (int mt = 0; mt < 4; mt++)
    #pragma unroll
    for (int nt = 0; nt < 4; nt++) {
      bool badcol = (nt == 3) && (lm > 0);
      #pragma unroll
      for (int reg = 0; reg < 4; reg++)
        s[mt][nt][reg] = badcol ? -1e30f : s[mt][nt][reg] * scale;
    }
  // softmax over keys (pos_bias cancels exactly)
  #pragma unroll
  for (int mt = 0; mt < 4; mt++) {
    #pragma unroll
    for (int reg = 0; reg < 4; reg++) {
      float mx = fmaxf(fmaxf(s[mt][0][reg], s[mt][1][reg]),
                       fmaxf(s[mt][2][reg], s[mt][3][reg]));
      #pragma unroll
      for (int off = 1; off < 16; off <<= 1) mx = fmaxf(mx, __shfl_xor(mx, off));
      float sum = 0.0f;
      #pragma unroll
      for (int nt = 0; nt < 4; nt++) {
        float e = __expf(s[mt][nt][reg] - mx);
        s[mt][nt][reg] = e;
        sum += e;
      }
      #pragma unroll
      for (int off = 1; off < 16; off <<= 1) sum += __shfl_xor(sum, off);
      float inv = 1.0f / sum;
      #pragma unroll
      for (int nt = 0; nt < 4; nt++) s[mt][nt][reg] *= inv;
    }
  }
  // P (bf16) -> LDS row-major [p][r2]
  #pragma unroll
  for (int mt = 0; mt < 4; mt++)
    #pragma unroll
    for (int nt = 0; nt < 4; nt++)
      #pragma unroll
      for (int reg = 0; reg < 4; reg++) {
        int p = mt * 16 + lg * 4 + reg;
        if (p < WS2) P[p * P_LD + nt * 16 + lm] = f2bf(s[mt][nt][reg]);
      }
  // O = P V
  f32x4 o[4][2];
  #pragma unroll
  for (int mt = 0; mt < 4; mt++)
    #pragma unroll
    for (int nt2 = 0; nt2 < 2; nt2++) o[mt][nt2] = (f32x4){0.f, 0.f, 0.f, 0.f};
  #pragma unroll
  for (int ks = 0; ks < 2; ks++) {
    bf16x8 vf[2];
    #pragma unroll
    for (int nt2 = 0; nt2 < 2; nt2++)
      vf[nt2] = *(const bf16x8*)(Vt + (nt2 * 16 + lm) * V_LD + ks * 32 + lg * 8);
    #pragma unroll
    for (int mt = 0; mt < 4; mt++) {
      bf16x8 af = *(const bf16x8*)(P + (mt * 16 + lm) * P_LD + ks * 32 + lg * 8);
      #pragma unroll
      for (int nt2 = 0; nt2 < 2; nt2++)
        o[mt][nt2] = __builtin_amdgcn_mfma_f32_16x16x32_bf16(af, vf[nt2], o[mt][nt2], 0, 0, 0);
    }
  }
  // O -> LDS assembly (P region dead after PV; same-wave ds program order)
  #pragma unroll
  for (int mt = 0; mt < 4; mt++)
    #pragma unroll
    for (int reg = 0; reg < 4; reg++) {
      int p = mt * 16 + lg * 4 + reg;
      if (p < WS2) {
        #pragma unroll
        for (int nt2 = 0; nt2 < 2; nt2++)
          Ow[p * OW_LD + nt2 * 16 + lm] = o[mt][nt2][reg];
      }
    }
  // full-line stores: 8 lanes x uint4 = one complete 128B line per row
  for (int idx = lane; idx < WS2 * 8; idx += 64) {
    int p = idx >> 3, seg = idx & 7;
    *(uint4*)(ob + (size_t)p * (NWIN * HDD) + seg * 4) =
        *(const uint4*)(Ow + p * OW_LD + seg * 4);
  }
}

__launch_bounds__(256, 3)
__global__ void k2_attn(const unsigned short* __restrict__ qkv_ws,
                        float* __restrict__ o_ws) {
  __shared__ __align__(16) unsigned short lds[V_OFF + 4 * V_WAVE];  // 46656 B
  const int tid = threadIdx.x;
  const int lane = tid & 63;
  const int wv = tid >> 6;
  const int lm = lane & 15;
  const int lg = lane >> 4;
  const int m = blockIdx.x;
  const int b = blockIdx.y;
  const unsigned short* wsrc = qkv_ws + (size_t)(b * NWIN + m) * QKV_SHORTS_PER_WIN;
  unsigned short* P  = lds + wv * P_WAVE;
  unsigned short* Vt = lds + V_OFF + wv * V_WAVE;
  float* Ow = (float*)P;

  // zero Vt once (rows r>=49 must stay 0 across both heads)
  {
    unsigned int* vz = (unsigned int*)Vt;
    #pragma unroll
    for (int i = 0; i < 18; i++) vz[i * 64 + lane] = 0u;
  }

  const int h0 = 2 * wv, h1 = 2 * wv + 1;
  // V(h0) global loads (uint4 = 8 shorts), held in regs until LDS zeroing done
  const int vr = lane >> 2;            // 0..15 row group base
  const int vd0 = (lane & 3) * 8;      // d0 in {0,8,16,24}
  uint4 vbuf[4];
  #pragma unroll
  for (int i = 0; i < 4; i++) {
    int r = vr + i * 16;               // rows 0..63; clamp >=49 (overwritten? no—skip on unpack)
    int rc = (r > 48) ? 48 : r;
    vbuf[i] = *(const uint4*)(wsrc + (size_t)rc * 768 + 512 + h0 * HDD + vd0);
  }
  // Q/K fragments for BOTH heads (16 loads in flight)
  bf16x8 qf[2][4], kf[2][4];
  #pragma unroll
  for (int t = 0; t < 4; t++) {
    int r = t * 16 + lm; if (r > 48) r = 48;
    qf[0][t] = *(const bf16x8*)(wsrc + (size_t)r * 768 + h0 * HDD + lg * 8);
    kf[0][t] = *(const bf16x8*)(wsrc + (size_t)r * 768 + 256 + h0 * HDD + lg * 8);
    qf[1][t] = *(const bf16x8*)(wsrc + (size_t)r * 768 + h1 * HDD + lg * 8);
    kf[1][t] = *(const bf16x8*)(wsrc + (size_t)r * 768 + 256 + h1 * HDD + lg * 8);
  }
  // unpack V(h0) -> Vt (rows >=49 skipped; region pre-zeroed)
  #pragma unroll
  for (int i = 0; i < 4; i++) {
    int r = vr + i * 16;
    if (r < WS2) {
      unsigned int uu[4] = { vbuf[i].x, vbuf[i].y, vbuf[i].z, vbuf[i].w };
      #pragma unroll
      for (int k = 0; k < 4; k++) {
        Vt[(vd0 + 2 * k) * V_LD + r]     = (unsigned short)(uu[k] & 0xffffu);
        Vt[(vd0 + 2 * k + 1) * V_LD + r] = (unsigned short)(uu[k] >> 16);
      }
    }
  }

  float* ob0 = o_ws + (size_t)b * O_PER_B + ((size_t)h0 * WS2 * NWIN + m) * HDD;
  float* ob1 = o_ws + (size_t)b * O_PER_B + ((size_t)h1 * WS2 * NWIN + m) * HDD;

  // head h0 (V(h1) loads issued inside via early placement below)
  // issue V(h1) loads NOW so they fly under h0's compute
  uint4 vbuf2[4];
  #pragma unroll
  for (int i = 0; i < 4; i++) {
    int r = vr + i * 16;
    int rc = (r > 48) ? 48 : r;
    vbuf2[i] = *(const uint4*)(wsrc + (size_t)rc * 768 + 512 + h1 * HDD + vd0);
  }

  attn_head(qf[0], kf[0], P, Vt, Ow, ob0, lane, lm, lg);

  // unpack V(h1) (Vt free after PV(h0); same-wave ds program order)
  #pragma unroll
  for (int i = 0; i < 4; i++) {
    int r = vr + i * 16;
    if (r < WS2) {
      unsigned int uu[4] = { vbuf2[i].x, vbuf2[i].y, vbuf2[i].z, vbuf2[i].w };
      #pragma unroll
      for (int k = 0; k < 4; k++) {
        Vt[(vd0 + 2 * k) * V_LD + r]     = (unsigned short)(uu[k] & 0xffffu);
        Vt[(vd0 + 2 * k + 1) * V_LD + r] = (unsigned short)(uu[k] >> 16);
      }
    }
  }

  attn_head(qf[1], kf[1], P, Vt, Ow, ob1, lane, lm, lg);
}

// ---------- K3: conv (49-tap over p') + projection ----------
__global__ void k3_conv_proj(const float* __restrict__ o_ws,
                             const float* __restrict__ conv_w,
                             const float* __restrict__ conv_b,
                             const float* __restrict__ w_proj,
                             const float* __restrict__ b_proj,
                             float* __restrict__ out) {
  __shared__ float yv[CC];
  __shared__ float cw[WS2];
  const int tid = threadIdx.x;
  const int np = blockIdx.x;
  const int b = blockIdx.y;
  if (tid < WS2) cw[tid] = conv_w[tid];
  __syncthreads();
  const float* base = o_ws + (size_t)b * O_PER_B + (size_t)np * (WS2 * CC);
  float acc = conv_b[0];
  for (int p = 0; p < WS2; p++)
    acc += cw[p] * base[p * CC + tid];
  yv[tid] = acc;
  __syncthreads();
  const float4* y4 = (const float4*)yv;
  const float4* w4 = (const float4*)(w_proj + (size_t)tid * CC);
  float s = b_proj[tid];
  float s2 = 0.0f;
  #pragma unroll 8
  for (int c4 = 0; c4 < 64; c4++) {
    float4 a = y4[c4], wv2 = w4[c4];
    s2 += a.x * wv2.x + a.y * wv2.y + a.z * wv2.z + a.w * wv2.w;
  }
  out[((size_t)(b * NWIN + np)) * CC + tid] = s + s2;
}

extern "C" void kernel_launch(void* const* d_in, const int* in_sizes, int n_in,
                              void* d_out, int out_size, void* d_ws, size_t ws_size,
                              hipStream_t stream) {
  const float* x        = (const float*)d_in[0];
  const float* polys    = (const float*)d_in[1];
  const float* w_qkv    = (const float*)d_in[2];
  const float* b_qkv    = (const float*)d_in[3];
  const float* w_proj   = (const float*)d_in[4];
  const float* b_proj   = (const float*)d_in[5];
  const float* conv_w   = (const float*)d_in[6];
  const float* conv_b   = (const float*)d_in[7];
  float* out = (float*)d_out;

  char* ws = (char*)d_ws;
  float* xT = (float*)ws;
  unsigned short* wbp = (unsigned short*)(ws + XT_BYTES);
  unsigned short* qkv_ws = (unsigned short*)(ws + XT_BYTES + WB_BYTES);
  float* o_ws = (float*)(ws + XT_BYTES + WB_BYTES + QKV_BYTES);

  hipLaunchKernelGGL(k0_prep, dim3(2145), dim3(256), 0, stream, x, xT, w_qkv, wbp);
  hipLaunchKernelGGL(k1_sample_qkv, dim3(NWIN, B_), dim3(256), 0, stream,
                     xT, polys, wbp, b_qkv, qkv_ws);
  hipLaunchKernelGGL(k2_attn, dim3(NWIN, B_), dim3(256), 0, stream,
                     qkv_ws, o_ws);
  hipLaunchKernelGGL(k3_conv_proj, dim3(NWIN, B_), dim3(256), 0, stream,
                     o_ws, conv_w, conv_b, w_proj, b_proj, out);
}

// Round 16
// 193.741 us; speedup vs baseline: 1.2523x; 1.0055x over previous
//
#include <hip/hip_runtime.h>
#include <hip/hip_bf16.h>

// Problem constants
#define B_    2
#define QN    100
#define NP    6
#define WS2   49
#define CC    256
#define NHH   8
#define HDD   32
#define NWIN  600            // Q*Np windows per batch
#define O_PER_B 7526400      // NH*WS2*NWIN*HD elements (now bf16 shorts)

// ws layout (bytes): xT fp32 (+1KB zero page) | wbp bf16 [48][8][64][8] | qkv bf16 | O bf16
#define XT_BYTES   (8388608 + 1024)
#define ZABS       2097152                  // element index of the zero page in xT
#define WB_BYTES   393216
#define QKV_SHORTS_PER_WIN (WS2 * 768)      // 37632 shorts
#define QKV_BYTES  (1200 * WS2 * 768 * 2)   // 90316800

#define SPB_LD 264   // bf16 sp row stride (shorts)
#define CW_LD  72    // per-wave C line-assembly row stride (144B rows, 16B-aligned)

typedef __attribute__((ext_vector_type(8))) short bf16x8;
typedef __attribute__((ext_vector_type(4))) float f32x4;

__device__ __forceinline__ unsigned short f2bf(float f) {
  union { float f; unsigned int i; } v; v.f = f;
  unsigned int x = v.i;
  x += 0x7fffu + ((x >> 16) & 1u);   // round-to-nearest-even
  return (unsigned short)(x >> 16);
}
__device__ __forceinline__ float bf2f(unsigned short u) {
  union { unsigned int i; float f; } v; v.i = ((unsigned int)u) << 16; return v.f;
}

// ---------- K0: x-transpose (0..2047) + w_qkv pack (2048..2143) + zero page (2144) ----------
__global__ void k0_prep(const float* __restrict__ x, float* __restrict__ xT,
                        const float* __restrict__ w_qkv, unsigned short* __restrict__ wbp) {
  __shared__ float tile[32][33];
  const int gb = blockIdx.x;
  if (gb < 2048) {
    int b   = gb >> 10;
    int rem = gb & 1023;
    int hw0 = (rem & 127) * 32;
    int c0  = (rem >> 7) * 32;
    int tx = threadIdx.x & 31, ty = threadIdx.x >> 5;   // 32x8
    const float* src = x + (size_t)b * CC * 4096;
    float* dst = xT + (size_t)b * 4096 * CC;
    #pragma unroll
    for (int i = ty; i < 32; i += 8)
      tile[i][tx] = src[(size_t)(c0 + i) * 4096 + hw0 + tx];
    __syncthreads();
    #pragma unroll
    for (int i = ty; i < 32; i += 8)
      dst[(size_t)(hw0 + i) * CC + c0 + tx] = tile[tx][i];
  } else if (gb < 2144) {
    int g = (gb - 2048) * 256 + threadIdx.x;      // 0..24575
    int lane = g & 63;
    int ks = (g >> 6) & 7;
    int nt = g >> 9;
    int n  = nt * 16 + (lane & 15);
    int k0 = ks * 32 + (lane >> 4) * 8;
    const float* src = w_qkv + (size_t)n * CC + k0;
    float4 lo = *(const float4*)(src);
    float4 hi = *(const float4*)(src + 4);
    unsigned short o[8] = { f2bf(lo.x), f2bf(lo.y), f2bf(lo.z), f2bf(lo.w),
                            f2bf(hi.x), f2bf(hi.y), f2bf(hi.z), f2bf(hi.w) };
    *(uint4*)(wbp + (size_t)g * 8) = *(uint4*)o;
  } else {
    xT[ZABS + threadIdx.x] = 0.0f;   // zero page for invalid bilinear corners
  }
}

// ---------- K1: per-window sample + MFMA QKV GEMM -> qkv_ws (bf16, [win][r][j]) ----------
// (r14-proven: phase-A uniform-work precompute + zero page, batch-4 sampling,
// bfrag register double-buffer, 16-row Cw full-line stores.)
__launch_bounds__(256, 3)
__global__ void k1_sample_qkv(const float* __restrict__ xT,
                              const float* __restrict__ polys,
                              const unsigned short* __restrict__ wbp,
                              const float* __restrict__ b_qkv,
                              unsigned short* __restrict__ qkv_ws) {
  __shared__ __align__(16) unsigned short spb[64 * SPB_LD];   // rows 49..63 zeroed
  __shared__ __align__(16) unsigned short Cwbuf[4][16 * CW_LD];
  __shared__ __align__(16) int   co_off[WS2][4];
  __shared__ __align__(16) float co_w[WS2][4];
  const int tid = threadIdx.x;
  const int m = blockIdx.x;
  const int b = blockIdx.y;

  // Phase A: per-row offsets + weights (grid scramble: n = m*49+r)
  if (tid < WS2) {
    int n = m * WS2 + tid;
    int q = n / (WS2 * NP);
    int p = (n / NP) % WS2;
    int a = n % NP;
    const float* pc = polys + (size_t)(b * QN + q) * 12;
    float al = (float)a * 0.2f;
    float py = pc[0];
    float px = pc[6];
    #pragma unroll
    for (int i = 1; i < 6; i++) { py = py * al + pc[i]; px = px * al + pc[6 + i]; }
    py = 2.0f * py - 1.0f;
    px = 2.0f * px - 1.0f;
    float gy = py + (2.0f * (-4.0f + (float)(p / 7) * (7.0f / 6.0f))) * (1.0f / 64.0f);
    float gx = px + (2.0f * (-4.0f + (float)(p % 7) * (7.0f / 6.0f))) * (1.0f / 64.0f);
    // NOTE the reference swap: fx from grid_y, fy from grid_x
    float fx = (gy + 1.0f) * 0.5f * 63.0f;
    float fy = (gx + 1.0f) * 0.5f * 63.0f;
    float x0 = floorf(fx), y0 = floorf(fy);
    float wx = fx - x0, wy = fy - y0;
    float x1 = x0 + 1.0f, y1 = y0 + 1.0f;
    int xi0 = (int)fminf(fmaxf(x0, 0.0f), 63.0f);
    int yi0 = (int)fminf(fmaxf(y0, 0.0f), 63.0f);
    int xi1 = (int)fminf(fmaxf(x1, 0.0f), 63.0f);
    int yi1 = (int)fminf(fmaxf(y1, 0.0f), 63.0f);
    bool vx0 = (x0 >= 0.0f) && (x0 <= 63.0f);
    bool vx1 = (x1 >= 0.0f) && (x1 <= 63.0f);
    bool vy0 = (y0 >= 0.0f) && (y0 <= 63.0f);
    bool vy1 = (y1 >= 0.0f) && (y1 <= 63.0f);
    const int bb = b * 4096;
    co_off[tid][0] = (vx0 && vy0) ? (bb + yi0 * 64 + xi0) * CC : ZABS;
    co_off[tid][1] = (vx1 && vy0) ? (bb + yi0 * 64 + xi1) * CC : ZABS;
    co_off[tid][2] = (vx0 && vy1) ? (bb + yi1 * 64 + xi0) * CC : ZABS;
    co_off[tid][3] = (vx1 && vy1) ? (bb + yi1 * 64 + xi1) * CC : ZABS;
    co_w[tid][0] = (1.0f - wy) * (1.0f - wx);
    co_w[tid][1] = (1.0f - wy) * wx;
    co_w[tid][2] = wy * (1.0f - wx);
    co_w[tid][3] = wy * wx;
  }
  // zero pad rows 49..63
  {
    unsigned int* z = (unsigned int*)(spb + WS2 * SPB_LD);
    for (int i = tid; i < 15 * SPB_LD / 2; i += 256) z[i] = 0u;
  }
  __syncthreads();

  // Phase B: bilinear sampling, thread = channel, batch-4 rows (16 loads in flight)
  for (int bi = 0; bi < 12; bi++) {
    const int rbase = bi * 4;
    float vv[4][4];
    #pragma unroll
    for (int k = 0; k < 4; k++) {
      int r = rbase + k;
      int4 off = *(const int4*)&co_off[r][0];
      vv[k][0] = xT[off.x + tid];
      vv[k][1] = xT[off.y + tid];
      vv[k][2] = xT[off.z + tid];
      vv[k][3] = xT[off.w + tid];
    }
    #pragma unroll
    for (int k = 0; k < 4; k++) {
      int r = rbase + k;
      float4 w = *(const float4*)&co_w[r][0];
      float s = vv[k][0] * w.x + vv[k][1] * w.y + vv[k][2] * w.z + vv[k][3] * w.w;
      spb[r * SPB_LD + tid] = f2bf(s);
    }
  }
  {  // tail row 48
    int4 off = *(const int4*)&co_off[48][0];
    float4 w = *(const float4*)&co_w[48][0];
    float s = xT[off.x + tid] * w.x + xT[off.y + tid] * w.y
            + xT[off.z + tid] * w.z + xT[off.w + tid] * w.w;
    spb[48 * SPB_LD + tid] = f2bf(s);
  }
  __syncthreads();

  // Phase C: MFMA GEMM. Wave wv owns N-tiles [wv*12,+12) in 3 chunks of 4.
  const int lane = tid & 63;
  const int wv = tid >> 6;
  const int lm = lane & 15;
  const int lg = lane >> 4;
  unsigned short* qd = qkv_ws + (size_t)(b * NWIN + m) * QKV_SHORTS_PER_WIN;
  unsigned short* Cw = &Cwbuf[wv][0];

  for (int jc = 0; jc < 3; jc++) {
    const int nt0 = wv * 12 + jc * 4;
    const int ncol0 = nt0 * 16 + lm;
    f32x4 acc[4][4];
    #pragma unroll
    for (int j4 = 0; j4 < 4; j4++) {
      float bias = b_qkv[ncol0 + j4 * 16];
      #pragma unroll
      for (int mt = 0; mt < 4; mt++) acc[mt][j4] = (f32x4){bias, bias, bias, bias};
    }
    // register double-buffer for B fragments (r12 proved removal costs ~17us)
    bf16x8 bnx[4];
    #pragma unroll
    for (int j4 = 0; j4 < 4; j4++)
      bnx[j4] = *(const bf16x8*)(wbp + (size_t)(((nt0 + j4) * 8 + 0) * 64 + lane) * 8);
    #pragma unroll
    for (int ks = 0; ks < 8; ks++) {
      bf16x8 bc[4];
      #pragma unroll
      for (int j4 = 0; j4 < 4; j4++) bc[j4] = bnx[j4];
      if (ks < 7) {
        #pragma unroll
        for (int j4 = 0; j4 < 4; j4++)
          bnx[j4] = *(const bf16x8*)(wbp + (size_t)(((nt0 + j4) * 8 + ks + 1) * 64 + lane) * 8);
      }
      bf16x8 af[4];
      #pragma unroll
      for (int mt = 0; mt < 4; mt++)
        af[mt] = *(const bf16x8*)(spb + (mt * 16 + lm) * SPB_LD + ks * 32 + lg * 8);
      #pragma unroll
      for (int j4 = 0; j4 < 4; j4++)
        #pragma unroll
        for (int mt = 0; mt < 4; mt++)
          acc[mt][j4] = __builtin_amdgcn_mfma_f32_16x16x32_bf16(af[mt], bc[j4], acc[mt][j4], 0, 0, 0);
    }
    // per-mt 16-row assembly + full-line stores (8 lines per uint4 instr)
    const int cbase = nt0 * 16;
    #pragma unroll
    for (int mt = 0; mt < 4; mt++) {
      #pragma unroll
      for (int reg = 0; reg < 4; reg++) {
        int rr = lg * 4 + reg;   // row within tile
        #pragma unroll
        for (int j4 = 0; j4 < 4; j4++)
          Cw[rr * CW_LD + j4 * 16 + lm] = f2bf(acc[mt][j4][reg]);
      }
      int r0 = mt * 16;
      #pragma unroll
      for (int half = 0; half < 2; half++) {
        int idx = half * 64 + lane;
        int r16 = idx >> 3;       // 0..15
        int seg = idx & 7;
        int r = r0 + r16;
        if (r < WS2)
          *(uint4*)(qd + (size_t)r * 768 + cbase + seg * 8) =
              *(const uint4*)(Cw + r16 * CW_LD + seg * 8);
      }
    }
  }
}

// ---------- K2: MFMA windowed attention, wave-per-head-pair, two-head pipeline ----------
// Round-16: O stored bf16 in BLOCK-CONTIGUOUS layout O_blk[b][m][hp][d]
// (hp=h*49+p): per-wave 6.3KB dense run -> trivially full-line stores, halves
// O write traffic. k3 inverts the scramble (verified mapping).
#define P_LD 72    // P row stride in shorts
#define V_LD 72    // Vt row stride in shorts
#define OW_LD 36   // O assembly row stride in floats
#define P_WAVE (WS2 * P_LD)          // 3528 shorts per wave
#define V_OFF  (4 * P_WAVE)          // 14112 shorts
#define V_WAVE (32 * V_LD)           // 2304 shorts per wave

__device__ __forceinline__ void attn_head(
    const bf16x8 qf[4], const bf16x8 kf[4],
    unsigned short* P, unsigned short* Vt, float* Ow, unsigned short* ob16,
    int lane, int lm, int lg) {
  const float scale = 0.17677669529663687f;  // 1/sqrt(32)
  // S = Q K^T
  f32x4 s[4][4];
  #pragma unroll
  for (int mt = 0; mt < 4; mt++)
    #pragma unroll
    for (int nt = 0; nt < 4; nt++) {
      s[mt][nt] = (f32x4){0.f, 0.f, 0.f, 0.f};
      s[mt][nt] = __builtin_amdgcn_mfma_f32_16x16x32_bf16(qf[mt], kf[nt], s[mt][nt], 0, 0, 0);
    }
  #pragma unroll
  for (int mt = 0; mt < 4; mt++)
    #pragma unroll
    for (int nt = 0; nt < 4; nt++) {
      bool badcol = (nt == 3) && (lm > 0);
      #pragma unroll
      for (int reg = 0; reg < 4; reg++)
        s[mt][nt][reg] = badcol ? -1e30f : s[mt][nt][reg] * scale;
    }
  // softmax over keys (pos_bias cancels exactly)
  #pragma unroll
  for (int mt = 0; mt < 4; mt++) {
    #pragma unroll
    for (int reg = 0; reg < 4; reg++) {
      float mx = fmaxf(fmaxf(s[mt][0][reg], s[mt][1][reg]),
                       fmaxf(s[mt][2][reg], s[mt][3][reg]));
      #pragma unroll
      for (int off = 1; off < 16; off <<= 1) mx = fmaxf(mx, __shfl_xor(mx, off));
      float sum = 0.0f;
      #pragma unroll
      for (int nt = 0; nt < 4; nt++) {
        float e = __expf(s[mt][nt][reg] - mx);
        s[mt][nt][reg] = e;
        sum += e;
      }
      #pragma unroll
      for (int off = 1; off < 16; off <<= 1) sum += __shfl_xor(sum, off);
      float inv = 1.0f / sum;
      #pragma unroll
      for (int nt = 0; nt < 4; nt++) s[mt][nt][reg] *= inv;
    }
  }
  // P (bf16) -> LDS row-major [p][r2]
  #pragma unroll
  for (int mt = 0; mt < 4; mt++)
    #pragma unroll
    for (int nt = 0; nt < 4; nt++)
      #pragma unroll
      for (int reg = 0; reg < 4; reg++) {
        int p = mt * 16 + lg * 4 + reg;
        if (p < WS2) P[p * P_LD + nt * 16 + lm] = f2bf(s[mt][nt][reg]);
      }
  // O = P V
  f32x4 o[4][2];
  #pragma unroll
  for (int mt = 0; mt < 4; mt++)
    #pragma unroll
    for (int nt2 = 0; nt2 < 2; nt2++) o[mt][nt2] = (f32x4){0.f, 0.f, 0.f, 0.f};
  #pragma unroll
  for (int ks = 0; ks < 2; ks++) {
    bf16x8 vf[2];
    #pragma unroll
    for (int nt2 = 0; nt2 < 2; nt2++)
      vf[nt2] = *(const bf16x8*)(Vt + (nt2 * 16 + lm) * V_LD + ks * 32 + lg * 8);
    #pragma unroll
    for (int mt = 0; mt < 4; mt++) {
      bf16x8 af = *(const bf16x8*)(P + (mt * 16 + lm) * P_LD + ks * 32 + lg * 8);
      #pragma unroll
      for (int nt2 = 0; nt2 < 2; nt2++)
        o[mt][nt2] = __builtin_amdgcn_mfma_f32_16x16x32_bf16(af, vf[nt2], o[mt][nt2], 0, 0, 0);
    }
  }
  // O -> LDS assembly (P region dead after PV; same-wave ds program order)
  #pragma unroll
  for (int mt = 0; mt < 4; mt++)
    #pragma unroll
    for (int reg = 0; reg < 4; reg++) {
      int p = mt * 16 + lg * 4 + reg;
      if (p < WS2) {
        #pragma unroll
        for (int nt2 = 0; nt2 < 2; nt2++)
          Ow[p * OW_LD + nt2 * 16 + lm] = o[mt][nt2][reg];
      }
    }
  // pack bf16 + dense stores: 196 uint4 chunks = contiguous 6272B run
  for (int idx = lane; idx < WS2 * 4; idx += 64) {
    int p = idx >> 2, seg = idx & 3;
    const float* src = Ow + p * OW_LD + seg * 8;
    unsigned short o8[8];
    #pragma unroll
    for (int k = 0; k < 8; k++) o8[k] = f2bf(src[k]);
    *(uint4*)(ob16 + (size_t)idx * 8) = *(uint4*)o8;
  }
}

__launch_bounds__(256, 3)
__global__ void k2_attn(const unsigned short* __restrict__ qkv_ws,
                        unsigned short* __restrict__ o16) {
  __shared__ __align__(16) unsigned short lds[V_OFF + 4 * V_WAVE];  // 46656 B
  const int tid = threadIdx.x;
  const int lane = tid & 63;
  const int wv = tid >> 6;
  const int lm = lane & 15;
  const int lg = lane >> 4;
  const int m = blockIdx.x;
  const int b = blockIdx.y;
  const unsigned short* wsrc = qkv_ws + (size_t)(b * NWIN + m) * QKV_SHORTS_PER_WIN;
  unsigned short* P  = lds + wv * P_WAVE;
  unsigned short* Vt = lds + V_OFF + wv * V_WAVE;
  float* Ow = (float*)P;

  // zero Vt once (rows r>=49 must stay 0 across both heads)
  {
    unsigned int* vz = (unsigned int*)Vt;
    #pragma unroll
    for (int i = 0; i < 18; i++) vz[i * 64 + lane] = 0u;
  }

  const int h0 = 2 * wv, h1 = 2 * wv + 1;
  // V(h0) global loads (uint4 = 8 shorts)
  const int vr = lane >> 2;            // row group base
  const int vd0 = (lane & 3) * 8;      // d0 in {0,8,16,24}
  uint4 vbuf[4];
  #pragma unroll
  for (int i = 0; i < 4; i++) {
    int r = vr + i * 16;
    int rc = (r > 48) ? 48 : r;
    vbuf[i] = *(const uint4*)(wsrc + (size_t)rc * 768 + 512 + h0 * HDD + vd0);
  }
  // Q/K fragments for BOTH heads (16 loads in flight)
  bf16x8 qf[2][4], kf[2][4];
  #pragma unroll
  for (int t = 0; t < 4; t++) {
    int r = t * 16 + lm; if (r > 48) r = 48;
    qf[0][t] = *(const bf16x8*)(wsrc + (size_t)r * 768 + h0 * HDD + lg * 8);
    kf[0][t] = *(const bf16x8*)(wsrc + (size_t)r * 768 + 256 + h0 * HDD + lg * 8);
    qf[1][t] = *(const bf16x8*)(wsrc + (size_t)r * 768 + h1 * HDD + lg * 8);
    kf[1][t] = *(const bf16x8*)(wsrc + (size_t)r * 768 + 256 + h1 * HDD + lg * 8);
  }
  // unpack V(h0) -> Vt (rows >=49 skipped; region pre-zeroed)
  #pragma unroll
  for (int i = 0; i < 4; i++) {
    int r = vr + i * 16;
    if (r < WS2) {
      unsigned int uu[4] = { vbuf[i].x, vbuf[i].y, vbuf[i].z, vbuf[i].w };
      #pragma unroll
      for (int k = 0; k < 4; k++) {
        Vt[(vd0 + 2 * k) * V_LD + r]     = (unsigned short)(uu[k] & 0xffffu);
        Vt[(vd0 + 2 * k + 1) * V_LD + r] = (unsigned short)(uu[k] >> 16);
      }
    }
  }

  // block-contiguous O: base + h*49*32 shorts
  unsigned short* obase = o16 + ((size_t)(b * NWIN + m) * 392) * 32;
  unsigned short* ob0 = obase + (size_t)h0 * WS2 * HDD;
  unsigned short* ob1 = obase + (size_t)h1 * WS2 * HDD;

  // issue V(h1) loads NOW so they fly under h0's compute
  uint4 vbuf2[4];
  #pragma unroll
  for (int i = 0; i < 4; i++) {
    int r = vr + i * 16;
    int rc = (r > 48) ? 48 : r;
    vbuf2[i] = *(const uint4*)(wsrc + (size_t)rc * 768 + 512 + h1 * HDD + vd0);
  }

  attn_head(qf[0], kf[0], P, Vt, Ow, ob0, lane, lm, lg);

  // unpack V(h1) (Vt free after PV(h0); same-wave ds program order)
  #pragma unroll
  for (int i = 0; i < 4; i++) {
    int r = vr + i * 16;
    if (r < WS2) {
      unsigned int uu[4] = { vbuf2[i].x, vbuf2[i].y, vbuf2[i].z, vbuf2[i].w };
      #pragma unroll
      for (int k = 0; k < 4; k++) {
        Vt[(vd0 + 2 * k) * V_LD + r]     = (unsigned short)(uu[k] & 0xffffu);
        Vt[(vd0 + 2 * k + 1) * V_LD + r] = (unsigned short)(uu[k] >> 16);
      }
    }
  }

  attn_head(qf[1], kf[1], P, Vt, Ow, ob1, lane, lm, lg);
}

// ---------- K3: conv (49-tap, scramble-inverting gather) + projection ----------
// O_blk[b][m][hp][d] bf16. For output (n',p',c'): Q = n'*392 + p'*8 + (c'>>5);
// m = Q%600; hp = Q/600; d = c'&31.  (mapping verified at 4 corner cases)
__global__ void k3_conv_proj(const unsigned short* __restrict__ o16,
                             const float* __restrict__ conv_w,
                             const float* __restrict__ conv_b,
                             const float* __restrict__ w_proj,
                             const float* __restrict__ b_proj,
                             float* __restrict__ out) {
  __shared__ float yv[CC];
  __shared__ float cw[WS2];
  __shared__ int atab[392];
  const int tid = threadIdx.x;
  const int np = blockIdx.x;   // n' in [0,600)
  const int b = blockIdx.y;
  if (tid < WS2) cw[tid] = conv_w[tid];
  for (int i = tid; i < 392; i += 256) {
    int Q = np * 392 + i;
    int m = Q % 600;
    int hp = Q / 600;
    atab[i] = ((b * NWIN + m) * 392 + hp) * 32;
  }
  __syncthreads();
  const int cg = tid >> 5, dd = tid & 31;
  float acc = conv_b[0];
  for (int p = 0; p < WS2; p++)
    acc += cw[p] * bf2f(o16[(size_t)atab[p * 8 + cg] + dd]);
  yv[tid] = acc;
  __syncthreads();
  const float4* y4 = (const float4*)yv;
  const float4* w4 = (const float4*)(w_proj + (size_t)tid * CC);
  float s = b_proj[tid];
  float s2 = 0.0f;
  #pragma unroll 8
  for (int c4 = 0; c4 < 64; c4++) {
    float4 a = y4[c4], wv2 = w4[c4];
    s2 += a.x * wv2.x + a.y * wv2.y + a.z * wv2.z + a.w * wv2.w;
  }
  out[((size_t)(b * NWIN + np)) * CC + tid] = s + s2;
}

extern "C" void kernel_launch(void* const* d_in, const int* in_sizes, int n_in,
                              void* d_out, int out_size, void* d_ws, size_t ws_size,
                              hipStream_t stream) {
  const float* x        = (const float*)d_in[0];
  const float* polys    = (const float*)d_in[1];
  const float* w_qkv    = (const float*)d_in[2];
  const float* b_qkv    = (const float*)d_in[3];
  const float* w_proj   = (const float*)d_in[4];
  const float* b_proj   = (const float*)d_in[5];
  const float* conv_w   = (const float*)d_in[6];
  const float* conv_b   = (const float*)d_in[7];
  float* out = (float*)d_out;

  char* ws = (char*)d_ws;
  float* xT = (float*)ws;
  unsigned short* wbp = (unsigned short*)(ws + XT_BYTES);
  unsigned short* qkv_ws = (unsigned short*)(ws + XT_BYTES + WB_BYTES);
  unsigned short* o16 = (unsigned short*)(ws + XT_BYTES + WB_BYTES + QKV_BYTES);

  hipLaunchKernelGGL(k0_prep, dim3(2145), dim3(256), 0, stream, x, xT, w_qkv, wbp);
  hipLaunchKernelGGL(k1_sample_qkv, dim3(NWIN, B_), dim3(256), 0, stream,
                     xT, polys, wbp, b_qkv, qkv_ws);
  hipLaunchKernelGGL(k2_attn, dim3(NWIN, B_), dim3(256), 0, stream,
                     qkv_ws, o16);
  hipLaunchKernelGGL(k3_conv_proj, dim3(NWIN, B_), dim3(256), 0, stream,
                     o16, conv_w, conv_b, w_proj, b_proj, out);
}

// Round 17
// 170.532 us; speedup vs baseline: 1.4228x; 1.1361x over previous
//
#include <hip/hip_runtime.h>
#include <hip/hip_bf16.h>

// Problem constants
#define B_    2
#define QN    100
#define NP    6
#define WS2   49
#define CC    256
#define NHH   8
#define HDD   32
#define NWIN  600            // Q*Np windows per batch
#define O_PER_B 7526400      // NH*WS2*NWIN*HD elements (bf16 shorts)

// ws layout (bytes): xT fp32 (+1KB zero page) | wbp bf16 | wpT fp32 | qkv bf16 | O bf16
#define XT_BYTES   (8388608 + 1024)
#define ZABS       2097152                  // element index of the zero page in xT
#define WB_BYTES   393216
#define WPT_BYTES  262144
#define QKV_SHORTS_PER_WIN (WS2 * 768)      // 37632 shorts
#define QKV_BYTES  (1200 * WS2 * 768 * 2)   // 90316800

#define SPB_LD 264   // bf16 sp row stride (shorts)
#define CW_LD  72    // per-wave C line-assembly row stride (144B rows, 16B-aligned)

typedef __attribute__((ext_vector_type(8))) short bf16x8;
typedef __attribute__((ext_vector_type(4))) float f32x4;

__device__ __forceinline__ unsigned short f2bf(float f) {
  union { float f; unsigned int i; } v; v.f = f;
  unsigned int x = v.i;
  x += 0x7fffu + ((x >> 16) & 1u);   // round-to-nearest-even
  return (unsigned short)(x >> 16);
}
__device__ __forceinline__ float bf2f(unsigned short u) {
  union { unsigned int i; float f; } v; v.i = ((unsigned int)u) << 16; return v.f;
}

// ---------- K0: x-transpose (0..2047) + wbp pack (2048..2143) + zero page (2144)
//             + w_proj transpose (2145..2208) ----------
__global__ void k0_prep(const float* __restrict__ x, float* __restrict__ xT,
                        const float* __restrict__ w_qkv, unsigned short* __restrict__ wbp,
                        const float* __restrict__ w_proj, float* __restrict__ wpT) {
  __shared__ float tile[32][33];
  const int gb = blockIdx.x;
  if (gb < 2048) {
    int b   = gb >> 10;
    int rem = gb & 1023;
    int hw0 = (rem & 127) * 32;
    int c0  = (rem >> 7) * 32;
    int tx = threadIdx.x & 31, ty = threadIdx.x >> 5;   // 32x8
    const float* src = x + (size_t)b * CC * 4096;
    float* dst = xT + (size_t)b * 4096 * CC;
    #pragma unroll
    for (int i = ty; i < 32; i += 8)
      tile[i][tx] = src[(size_t)(c0 + i) * 4096 + hw0 + tx];
    __syncthreads();
    #pragma unroll
    for (int i = ty; i < 32; i += 8)
      dst[(size_t)(hw0 + i) * CC + c0 + tx] = tile[tx][i];
  } else if (gb < 2144) {
    // wbp[((nt*8+ks)*64+lane)*8+i] = bf16(w_qkv[nt*16+(lane&15)][ks*32+(lane>>4)*8+i])
    int g = (gb - 2048) * 256 + threadIdx.x;      // 0..24575
    int lane = g & 63;
    int ks = (g >> 6) & 7;
    int nt = g >> 9;
    int n  = nt * 16 + (lane & 15);
    int k0 = ks * 32 + (lane >> 4) * 8;
    const float* src = w_qkv + (size_t)n * CC + k0;
    float4 lo = *(const float4*)(src);
    float4 hi = *(const float4*)(src + 4);
    unsigned short o[8] = { f2bf(lo.x), f2bf(lo.y), f2bf(lo.z), f2bf(lo.w),
                            f2bf(hi.x), f2bf(hi.y), f2bf(hi.z), f2bf(hi.w) };
    *(uint4*)(wbp + (size_t)g * 8) = *(uint4*)o;
  } else if (gb == 2144) {
    xT[ZABS + threadIdx.x] = 0.0f;   // zero page for invalid bilinear corners
  } else {
    // wpT[c][j] = w_proj[j][c]  (kills the 64-segment gather in k3's proj loop)
    int t = gb - 2145;               // 0..63
    int r0 = (t >> 3) * 32;          // j tile
    int c0 = (t & 7) * 32;           // c tile
    int tx = threadIdx.x & 31, ty = threadIdx.x >> 5;
    #pragma unroll
    for (int i = ty; i < 32; i += 8)
      tile[i][tx] = w_proj[(size_t)(r0 + i) * CC + c0 + tx];
    __syncthreads();
    #pragma unroll
    for (int i = ty; i < 32; i += 8)
      wpT[(size_t)(c0 + i) * CC + r0 + tx] = tile[tx][i];
  }
}

// ---------- K1: per-window sample + MFMA QKV GEMM -> qkv_ws (bf16, [win][r][j]) ----------
// (r14-proven: phase-A uniform-work precompute + zero page, batch-4 sampling,
// bfrag register double-buffer, 16-row Cw full-line stores.)
__launch_bounds__(256, 3)
__global__ void k1_sample_qkv(const float* __restrict__ xT,
                              const float* __restrict__ polys,
                              const unsigned short* __restrict__ wbp,
                              const float* __restrict__ b_qkv,
                              unsigned short* __restrict__ qkv_ws) {
  __shared__ __align__(16) unsigned short spb[64 * SPB_LD];   // rows 49..63 zeroed
  __shared__ __align__(16) unsigned short Cwbuf[4][16 * CW_LD];
  __shared__ __align__(16) int   co_off[WS2][4];
  __shared__ __align__(16) float co_w[WS2][4];
  const int tid = threadIdx.x;
  const int m = blockIdx.x;
  const int b = blockIdx.y;

  // Phase A: per-row offsets + weights (grid scramble: n = m*49+r)
  if (tid < WS2) {
    int n = m * WS2 + tid;
    int q = n / (WS2 * NP);
    int p = (n / NP) % WS2;
    int a = n % NP;
    const float* pc = polys + (size_t)(b * QN + q) * 12;
    float al = (float)a * 0.2f;
    float py = pc[0];
    float px = pc[6];
    #pragma unroll
    for (int i = 1; i < 6; i++) { py = py * al + pc[i]; px = px * al + pc[6 + i]; }
    py = 2.0f * py - 1.0f;
    px = 2.0f * px - 1.0f;
    float gy = py + (2.0f * (-4.0f + (float)(p / 7) * (7.0f / 6.0f))) * (1.0f / 64.0f);
    float gx = px + (2.0f * (-4.0f + (float)(p % 7) * (7.0f / 6.0f))) * (1.0f / 64.0f);
    // NOTE the reference swap: fx from grid_y, fy from grid_x
    float fx = (gy + 1.0f) * 0.5f * 63.0f;
    float fy = (gx + 1.0f) * 0.5f * 63.0f;
    float x0 = floorf(fx), y0 = floorf(fy);
    float wx = fx - x0, wy = fy - y0;
    float x1 = x0 + 1.0f, y1 = y0 + 1.0f;
    int xi0 = (int)fminf(fmaxf(x0, 0.0f), 63.0f);
    int yi0 = (int)fminf(fmaxf(y0, 0.0f), 63.0f);
    int xi1 = (int)fminf(fmaxf(x1, 0.0f), 63.0f);
    int yi1 = (int)fminf(fmaxf(y1, 0.0f), 63.0f);
    bool vx0 = (x0 >= 0.0f) && (x0 <= 63.0f);
    bool vx1 = (x1 >= 0.0f) && (x1 <= 63.0f);
    bool vy0 = (y0 >= 0.0f) && (y0 <= 63.0f);
    bool vy1 = (y1 >= 0.0f) && (y1 <= 63.0f);
    const int bb = b * 4096;
    co_off[tid][0] = (vx0 && vy0) ? (bb + yi0 * 64 + xi0) * CC : ZABS;
    co_off[tid][1] = (vx1 && vy0) ? (bb + yi0 * 64 + xi1) * CC : ZABS;
    co_off[tid][2] = (vx0 && vy1) ? (bb + yi1 * 64 + xi0) * CC : ZABS;
    co_off[tid][3] = (vx1 && vy1) ? (bb + yi1 * 64 + xi1) * CC : ZABS;
    co_w[tid][0] = (1.0f - wy) * (1.0f - wx);
    co_w[tid][1] = (1.0f - wy) * wx;
    co_w[tid][2] = wy * (1.0f - wx);
    co_w[tid][3] = wy * wx;
  }
  // zero pad rows 49..63
  {
    unsigned int* z = (unsigned int*)(spb + WS2 * SPB_LD);
    for (int i = tid; i < 15 * SPB_LD / 2; i += 256) z[i] = 0u;
  }
  __syncthreads();

  // Phase B: bilinear sampling, thread = channel, batch-4 rows (16 loads in flight)
  for (int bi = 0; bi < 12; bi++) {
    const int rbase = bi * 4;
    float vv[4][4];
    #pragma unroll
    for (int k = 0; k < 4; k++) {
      int r = rbase + k;
      int4 off = *(const int4*)&co_off[r][0];
      vv[k][0] = xT[off.x + tid];
      vv[k][1] = xT[off.y + tid];
      vv[k][2] = xT[off.z + tid];
      vv[k][3] = xT[off.w + tid];
    }
    #pragma unroll
    for (int k = 0; k < 4; k++) {
      int r = rbase + k;
      float4 w = *(const float4*)&co_w[r][0];
      float s = vv[k][0] * w.x + vv[k][1] * w.y + vv[k][2] * w.z + vv[k][3] * w.w;
      spb[r * SPB_LD + tid] = f2bf(s);
    }
  }
  {  // tail row 48
    int4 off = *(const int4*)&co_off[48][0];
    float4 w = *(const float4*)&co_w[48][0];
    float s = xT[off.x + tid] * w.x + xT[off.y + tid] * w.y
            + xT[off.z + tid] * w.z + xT[off.w + tid] * w.w;
    spb[48 * SPB_LD + tid] = f2bf(s);
  }
  __syncthreads();

  // Phase C: MFMA GEMM. Wave wv owns N-tiles [wv*12,+12) in 3 chunks of 4.
  const int lane = tid & 63;
  const int wv = tid >> 6;
  const int lm = lane & 15;
  const int lg = lane >> 4;
  unsigned short* qd = qkv_ws + (size_t)(b * NWIN + m) * QKV_SHORTS_PER_WIN;
  unsigned short* Cw = &Cwbuf[wv][0];

  for (int jc = 0; jc < 3; jc++) {
    const int nt0 = wv * 12 + jc * 4;
    const int ncol0 = nt0 * 16 + lm;
    f32x4 acc[4][4];
    #pragma unroll
    for (int j4 = 0; j4 < 4; j4++) {
      float bias = b_qkv[ncol0 + j4 * 16];
      #pragma unroll
      for (int mt = 0; mt < 4; mt++) acc[mt][j4] = (f32x4){bias, bias, bias, bias};
    }
    // register double-buffer for B fragments (r12 proved removal costs ~17us)
    bf16x8 bnx[4];
    #pragma unroll
    for (int j4 = 0; j4 < 4; j4++)
      bnx[j4] = *(const bf16x8*)(wbp + (size_t)(((nt0 + j4) * 8 + 0) * 64 + lane) * 8);
    #pragma unroll
    for (int ks = 0; ks < 8; ks++) {
      bf16x8 bc[4];
      #pragma unroll
      for (int j4 = 0; j4 < 4; j4++) bc[j4] = bnx[j4];
      if (ks < 7) {
        #pragma unroll
        for (int j4 = 0; j4 < 4; j4++)
          bnx[j4] = *(const bf16x8*)(wbp + (size_t)(((nt0 + j4) * 8 + ks + 1) * 64 + lane) * 8);
      }
      bf16x8 af[4];
      #pragma unroll
      for (int mt = 0; mt < 4; mt++)
        af[mt] = *(const bf16x8*)(spb + (mt * 16 + lm) * SPB_LD + ks * 32 + lg * 8);
      #pragma unroll
      for (int j4 = 0; j4 < 4; j4++)
        #pragma unroll
        for (int mt = 0; mt < 4; mt++)
          acc[mt][j4] = __builtin_amdgcn_mfma_f32_16x16x32_bf16(af[mt], bc[j4], acc[mt][j4], 0, 0, 0);
    }
    // per-mt 16-row assembly + full-line stores (8 lines per uint4 instr)
    const int cbase = nt0 * 16;
    #pragma unroll
    for (int mt = 0; mt < 4; mt++) {
      #pragma unroll
      for (int reg = 0; reg < 4; reg++) {
        int rr = lg * 4 + reg;   // row within tile
        #pragma unroll
        for (int j4 = 0; j4 < 4; j4++)
          Cw[rr * CW_LD + j4 * 16 + lm] = f2bf(acc[mt][j4][reg]);
      }
      int r0 = mt * 16;
      #pragma unroll
      for (int half = 0; half < 2; half++) {
        int idx = half * 64 + lane;
        int r16 = idx >> 3;       // 0..15
        int seg = idx & 7;
        int r = r0 + r16;
        if (r < WS2)
          *(uint4*)(qd + (size_t)r * 768 + cbase + seg * 8) =
              *(const uint4*)(Cw + r16 * CW_LD + seg * 8);
      }
    }
  }
}

// ---------- K2: MFMA windowed attention, wave-per-head-pair, two-head pipeline ----------
// (r15 pipeline + r16 bf16 block-contiguous O; unchanged.)
#define P_LD 72    // P row stride in shorts
#define V_LD 72    // Vt row stride in shorts
#define OW_LD 36   // O assembly row stride in floats
#define P_WAVE (WS2 * P_LD)          // 3528 shorts per wave
#define V_OFF  (4 * P_WAVE)          // 14112 shorts
#define V_WAVE (32 * V_LD)           // 2304 shorts per wave

__device__ __forceinline__ void attn_head(
    const bf16x8 qf[4], const bf16x8 kf[4],
    unsigned short* P, unsigned short* Vt, float* Ow, unsigned short* ob16,
    int lane, int lm, int lg) {
  const float scale = 0.17677669529663687f;  // 1/sqrt(32)
  // S = Q K^T
  f32x4 s[4][4];
  #pragma unroll
  for (int mt = 0; mt < 4; mt++)
    #pragma unroll
    for (int nt = 0; nt < 4; nt++) {
      s[mt][nt] = (f32x4){0.f, 0.f, 0.f, 0.f};
      s[mt][nt] = __builtin_amdgcn_mfma_f32_16x16x32_bf16(qf[mt], kf[nt], s[mt][nt], 0, 0, 0);
    }
  #pragma unroll
  for (int mt = 0; mt < 4; mt++)
    #pragma unroll
    for (int nt = 0; nt < 4; nt++) {
      bool badcol = (nt == 3) && (lm > 0);
      #pragma unroll
      for (int reg = 0; reg < 4; reg++)
        s[mt][nt][reg] = badcol ? -1e30f : s[mt][nt][reg] * scale;
    }
  // softmax over keys (pos_bias cancels exactly)
  #pragma unroll
  for (int mt = 0; mt < 4; mt++) {
    #pragma unroll
    for (int reg = 0; reg < 4; reg++) {
      float mx = fmaxf(fmaxf(s[mt][0][reg], s[mt][1][reg]),
                       fmaxf(s[mt][2][reg], s[mt][3][reg]));
      #pragma unroll
      for (int off = 1; off < 16; off <<= 1) mx = fmaxf(mx, __shfl_xor(mx, off));
      float sum = 0.0f;
      #pragma unroll
      for (int nt = 0; nt < 4; nt++) {
        float e = __expf(s[mt][nt][reg] - mx);
        s[mt][nt][reg] = e;
        sum += e;
      }
      #pragma unroll
      for (int off = 1; off < 16; off <<= 1) sum += __shfl_xor(sum, off);
      float inv = 1.0f / sum;
      #pragma unroll
      for (int nt = 0; nt < 4; nt++) s[mt][nt][reg] *= inv;
    }
  }
  // P (bf16) -> LDS row-major [p][r2]
  #pragma unroll
  for (int mt = 0; mt < 4; mt++)
    #pragma unroll
    for (int nt = 0; nt < 4; nt++)
      #pragma unroll
      for (int reg = 0; reg < 4; reg++) {
        int p = mt * 16 + lg * 4 + reg;
        if (p < WS2) P[p * P_LD + nt * 16 + lm] = f2bf(s[mt][nt][reg]);
      }
  // O = P V
  f32x4 o[4][2];
  #pragma unroll
  for (int mt = 0; mt < 4; mt++)
    #pragma unroll
    for (int nt2 = 0; nt2 < 2; nt2++) o[mt][nt2] = (f32x4){0.f, 0.f, 0.f, 0.f};
  #pragma unroll
  for (int ks = 0; ks < 2; ks++) {
    bf16x8 vf[2];
    #pragma unroll
    for (int nt2 = 0; nt2 < 2; nt2++)
      vf[nt2] = *(const bf16x8*)(Vt + (nt2 * 16 + lm) * V_LD + ks * 32 + lg * 8);
    #pragma unroll
    for (int mt = 0; mt < 4; mt++) {
      bf16x8 af = *(const bf16x8*)(P + (mt * 16 + lm) * P_LD + ks * 32 + lg * 8);
      #pragma unroll
      for (int nt2 = 0; nt2 < 2; nt2++)
        o[mt][nt2] = __builtin_amdgcn_mfma_f32_16x16x32_bf16(af, vf[nt2], o[mt][nt2], 0, 0, 0);
    }
  }
  // O -> LDS assembly (P region dead after PV; same-wave ds program order)
  #pragma unroll
  for (int mt = 0; mt < 4; mt++)
    #pragma unroll
    for (int reg = 0; reg < 4; reg++) {
      int p = mt * 16 + lg * 4 + reg;
      if (p < WS2) {
        #pragma unroll
        for (int nt2 = 0; nt2 < 2; nt2++)
          Ow[p * OW_LD + nt2 * 16 + lm] = o[mt][nt2][reg];
      }
    }
  // pack bf16 + dense stores: contiguous 6272B run per head
  for (int idx = lane; idx < WS2 * 4; idx += 64) {
    int p = idx >> 2, seg = idx & 3;
    const float* src = Ow + p * OW_LD + seg * 8;
    unsigned short o8[8];
    #pragma unroll
    for (int k = 0; k < 8; k++) o8[k] = f2bf(src[k]);
    *(uint4*)(ob16 + (size_t)idx * 8) = *(uint4*)o8;
  }
}

__launch_bounds__(256, 3)
__global__ void k2_attn(const unsigned short* __restrict__ qkv_ws,
                        unsigned short* __restrict__ o16) {
  __shared__ __align__(16) unsigned short lds[V_OFF + 4 * V_WAVE];  // 46656 B
  const int tid = threadIdx.x;
  const int lane = tid & 63;
  const int wv = tid >> 6;
  const int lm = lane & 15;
  const int lg = lane >> 4;
  const int m = blockIdx.x;
  const int b = blockIdx.y;
  const unsigned short* wsrc = qkv_ws + (size_t)(b * NWIN + m) * QKV_SHORTS_PER_WIN;
  unsigned short* P  = lds + wv * P_WAVE;
  unsigned short* Vt = lds + V_OFF + wv * V_WAVE;
  float* Ow = (float*)P;

  // zero Vt once (rows r>=49 must stay 0 across both heads)
  {
    unsigned int* vz = (unsigned int*)Vt;
    #pragma unroll
    for (int i = 0; i < 18; i++) vz[i * 64 + lane] = 0u;
  }

  const int h0 = 2 * wv, h1 = 2 * wv + 1;
  // V(h0) global loads (uint4 = 8 shorts)
  const int vr = lane >> 2;            // row group base
  const int vd0 = (lane & 3) * 8;      // d0 in {0,8,16,24}
  uint4 vbuf[4];
  #pragma unroll
  for (int i = 0; i < 4; i++) {
    int r = vr + i * 16;
    int rc = (r > 48) ? 48 : r;
    vbuf[i] = *(const uint4*)(wsrc + (size_t)rc * 768 + 512 + h0 * HDD + vd0);
  }
  // Q/K fragments for BOTH heads (16 loads in flight)
  bf16x8 qf[2][4], kf[2][4];
  #pragma unroll
  for (int t = 0; t < 4; t++) {
    int r = t * 16 + lm; if (r > 48) r = 48;
    qf[0][t] = *(const bf16x8*)(wsrc + (size_t)r * 768 + h0 * HDD + lg * 8);
    kf[0][t] = *(const bf16x8*)(wsrc + (size_t)r * 768 + 256 + h0 * HDD + lg * 8);
    qf[1][t] = *(const bf16x8*)(wsrc + (size_t)r * 768 + h1 * HDD + lg * 8);
    kf[1][t] = *(const bf16x8*)(wsrc + (size_t)r * 768 + 256 + h1 * HDD + lg * 8);
  }
  // unpack V(h0) -> Vt (rows >=49 skipped; region pre-zeroed)
  #pragma unroll
  for (int i = 0; i < 4; i++) {
    int r = vr + i * 16;
    if (r < WS2) {
      unsigned int uu[4] = { vbuf[i].x, vbuf[i].y, vbuf[i].z, vbuf[i].w };
      #pragma unroll
      for (int k = 0; k < 4; k++) {
        Vt[(vd0 + 2 * k) * V_LD + r]     = (unsigned short)(uu[k] & 0xffffu);
        Vt[(vd0 + 2 * k + 1) * V_LD + r] = (unsigned short)(uu[k] >> 16);
      }
    }
  }

  // block-contiguous O: base + h*49*32 shorts
  unsigned short* obase = o16 + ((size_t)(b * NWIN + m) * 392) * 32;
  unsigned short* ob0 = obase + (size_t)h0 * WS2 * HDD;
  unsigned short* ob1 = obase + (size_t)h1 * WS2 * HDD;

  // issue V(h1) loads NOW so they fly under h0's compute
  uint4 vbuf2[4];
  #pragma unroll
  for (int i = 0; i < 4; i++) {
    int r = vr + i * 16;
    int rc = (r > 48) ? 48 : r;
    vbuf2[i] = *(const uint4*)(wsrc + (size_t)rc * 768 + 512 + h1 * HDD + vd0);
  }

  attn_head(qf[0], kf[0], P, Vt, Ow, ob0, lane, lm, lg);

  // unpack V(h1) (Vt free after PV(h0); same-wave ds program order)
  #pragma unroll
  for (int i = 0; i < 4; i++) {
    int r = vr + i * 16;
    if (r < WS2) {
      unsigned int uu[4] = { vbuf2[i].x, vbuf2[i].y, vbuf2[i].z, vbuf2[i].w };
      #pragma unroll
      for (int k = 0; k < 4; k++) {
        Vt[(vd0 + 2 * k) * V_LD + r]     = (unsigned short)(uu[k] & 0xffffu);
        Vt[(vd0 + 2 * k + 1) * V_LD + r] = (unsigned short)(uu[k] >> 16);
      }
    }
  }

  attn_head(qf[1], kf[1], P, Vt, Ow, ob1, lane, lm, lg);
}

// ---------- K3: conv (49-tap, scramble-inverting gather) + projection (wpT, coalesced) ----------
// O_blk[b][m][hp][d] bf16. For output (n',p',c'): Q = n'*392 + p'*8 + (c'>>5);
// m = Q%600; hp = Q/600; d = c'&31.
__global__ void k3_conv_proj(const unsigned short* __restrict__ o16,
                             const float* __restrict__ conv_w,
                             const float* __restrict__ conv_b,
                             const float* __restrict__ wpT,
                             const float* __restrict__ b_proj,
                             float* __restrict__ out) {
  __shared__ float yv[CC];
  __shared__ float cw[WS2];
  __shared__ int atab[392];
  const int tid = threadIdx.x;
  const int np = blockIdx.x;   // n' in [0,600)
  const int b = blockIdx.y;
  if (tid < WS2) cw[tid] = conv_w[tid];
  for (int i = tid; i < 392; i += 256) {
    int Q = np * 392 + i;
    int m = Q % 600;
    int hp = Q / 600;
    atab[i] = ((b * NWIN + m) * 392 + hp) * 32;
  }
  __syncthreads();
  const int cg = tid >> 5, dd = tid & 31;
  float acc = conv_b[0];
  for (int p = 0; p < WS2; p++)
    acc += cw[p] * bf2f(o16[(size_t)atab[p * 8 + cg] + dd]);
  yv[tid] = acc;
  __syncthreads();
  // proj: out[j=tid] = b_proj[j] + sum_c yv[c] * wpT[c][j]  (lane-consecutive loads)
  const float* wp = wpT + tid;
  float a0 = 0.0f, a1 = 0.0f, a2 = 0.0f, a3 = 0.0f;
  #pragma unroll 8
  for (int c = 0; c < CC; c += 4) {
    float4 y4 = *(const float4*)&yv[c];
    a0 += y4.x * wp[(c + 0) * CC];
    a1 += y4.y * wp[(c + 1) * CC];
    a2 += y4.z * wp[(c + 2) * CC];
    a3 += y4.w * wp[(c + 3) * CC];
  }
  out[((size_t)(b * NWIN + np)) * CC + tid] = b_proj[tid] + ((a0 + a1) + (a2 + a3));
}

extern "C" void kernel_launch(void* const* d_in, const int* in_sizes, int n_in,
                              void* d_out, int out_size, void* d_ws, size_t ws_size,
                              hipStream_t stream) {
  const float* x        = (const float*)d_in[0];
  const float* polys    = (const float*)d_in[1];
  const float* w_qkv    = (const float*)d_in[2];
  const float* b_qkv    = (const float*)d_in[3];
  const float* w_proj   = (const float*)d_in[4];
  const float* b_proj   = (const float*)d_in[5];
  const float* conv_w   = (const float*)d_in[6];
  const float* conv_b   = (const float*)d_in[7];
  float* out = (float*)d_out;

  char* ws = (char*)d_ws;
  float* xT = (float*)ws;
  unsigned short* wbp = (unsigned short*)(ws + XT_BYTES);
  float* wpT = (float*)(ws + XT_BYTES + WB_BYTES);
  unsigned short* qkv_ws = (unsigned short*)(ws + XT_BYTES + WB_BYTES + WPT_BYTES);
  unsigned short* o16 = (unsigned short*)(ws + XT_BYTES + WB_BYTES + WPT_BYTES + QKV_BYTES);

  hipLaunchKernelGGL(k0_prep, dim3(2209), dim3(256), 0, stream, x, xT, w_qkv, wbp, w_proj, wpT);
  hipLaunchKernelGGL(k1_sample_qkv, dim3(NWIN, B_), dim3(256), 0, stream,
                     xT, polys, wbp, b_qkv, qkv_ws);
  hipLaunchKernelGGL(k2_attn, dim3(NWIN, B_), dim3(256), 0, stream,
                     qkv_ws, o16);
  hipLaunchKernelGGL(k3_conv_proj, dim3(NWIN, B_), dim3(256), 0, stream,
                     o16, conv_w, conv_b, wpT, b_proj, out);
}